// Round 11
// baseline (169.763 us; speedup 1.0000x reference)
//
#include <hip/hip_runtime.h>
#include <math.h>
#include <type_traits>

#define CH 512
#define CQ 64
#define HH 64
#define WW 64
#define PP (HH*WW)   // 4096
#define BB 8

typedef __bf16 bf16x8 __attribute__((ext_vector_type(8)));
typedef __bf16 bf16x4 __attribute__((ext_vector_type(4)));
typedef float  f32x4  __attribute__((ext_vector_type(4)));

// ---- LDS helpers (inline asm; keep asm ds ops and compiler ds ops in
// ---- disjoint regions, one lgkmcnt(0)+sched_barrier(0) before MFMAs) ----
__device__ __forceinline__ unsigned lds_off(const void* p) {
  return (unsigned)(size_t)(__attribute__((address_space(3))) const void*)p;
}
__device__ __forceinline__ bf16x4 ds_tr16(unsigned addr) {
  bf16x4 r;
  asm volatile("ds_read_b64_tr_b16 %0, %1" : "=v"(r) : "v"(addr));
  return r;
}

// ---------------------------------------------------------------------------
// proj_body: one 128xBN tile of Y[m,o] = sum_c X[b,c,p]*W[o,c] + bias[o].
// 512 thr, 2x4 wave grid, wave tile 64x(FN*16); dbuf LDS; static depth-2
// A prefetch (named ra0/ra1, phase-unrolled; rule-#20 safe). Plain bf16.
// FN=2 -> BN=128 (v);  FN=1 -> BN=64 (q,k).
// ---------------------------------------------------------------------------
template<int FN, int NOUT, typename OutT>
__device__ __forceinline__ void proj_body(
    __bf16* AsBase, __bf16* BsBase,
    const float* __restrict__ X, const float* __restrict__ W,
    const float* __restrict__ bias, OutT* __restrict__ Y,
    int mblk, int nblk)
{
  constexpr int BM = 128;
  constexpr int BN = FN * 64;
  constexpr int BE = (BN * 32) / 512;   // B elems/thread: 8 (v) or 4 (q/k)
  typedef __bf16 (*TileA)[BM][40];
  typedef __bf16 (*TileB)[BN][40];
  TileA As = (TileA)AsBase;   // [2][128][40]
  TileB Bs = (TileB)BsBase;   // [2][BN][40]

  const int tid = threadIdx.x;
  const int b     = mblk >> 12;             // BM divides 4096
  const int pbase = mblk & 4095;
  const float* Xb = X + (size_t)b * CH * PP;

  const int l  = tid & 63;
  const int wv = tid >> 6;                  // 0..7
  const int wr = wv >> 2, wc = wv & 3;      // 2 x 4 wave grid
  const int lm = l & 15, lk = l >> 4;

  // A: one 8-elem group per thread
  const int ma = tid & 127;
  const int ka = (tid >> 7) * 8;
  // B: one group per thread (8 elems for v, 4 for q/k)
  const int nb = (BE == 8) ? (tid & 127) : (tid & 63);
  const int kb = (BE == 8) ? ((tid >> 7) * 8) : ((tid >> 6) * 4);

  float ra0[8], ra1[8];   // depth-2 A prefetch (named, static idx)
  float rb[BE];           // depth-1 B prefetch

  auto loadA = [&](float (&ra)[8], int c0) {
    #pragma unroll
    for (int jj = 0; jj < 8; ++jj)
      ra[jj] = Xb[(size_t)(c0 + ka + jj) * PP + pbase + ma];
  };
  auto loadB = [&](int c0) {
    const float* src = W + (size_t)(nblk + nb) * CH + c0 + kb;
    float4 f0 = *(const float4*)src;
    rb[0]=f0.x; rb[1]=f0.y; rb[2]=f0.z; rb[3]=f0.w;
    if constexpr (BE == 8) {
      float4 f1 = *(const float4*)(src + 4);
      rb[4]=f1.x; rb[5]=f1.y; rb[6]=f1.z; rb[7]=f1.w;
    }
  };

  f32x4 acc[4][FN];
  #pragma unroll
  for (int j = 0; j < FN; ++j) {
    float bvj = bias[nblk + wc*FN*16 + j*16 + lm];
    #pragma unroll
    for (int i = 0; i < 4; ++i) {
      acc[i][j][0] = bvj; acc[i][j][1] = bvj;
      acc[i][j][2] = bvj; acc[i][j][3] = bvj;
    }
  }

  auto phase = [&](int t, auto par_c, float (&ra)[8]) {
    constexpr int PAR = decltype(par_c)::value;
    {
      bf16x8 hv;
      #pragma unroll
      for (int jj = 0; jj < 8; ++jj) hv[jj] = (__bf16)ra[jj];
      *(bf16x8*)&As[PAR][ma][ka] = hv;
    }
    if constexpr (BE == 8) {
      bf16x8 hv;
      #pragma unroll
      for (int jj = 0; jj < 8; ++jj) hv[jj] = (__bf16)rb[jj];
      *(bf16x8*)&Bs[PAR][nb][kb] = hv;
    } else {
      bf16x4 hv;
      #pragma unroll
      for (int jj = 0; jj < 4; ++jj) hv[jj] = (__bf16)rb[jj];
      *(bf16x4*)&Bs[PAR][nb][kb] = hv;
    }
    __syncthreads();
    if (t < 15) loadB((t+1)*32);
    if (t < 14) loadA(ra, (t+2)*32);
    bf16x8 af[4], bfr[FN];
    #pragma unroll
    for (int i = 0; i < 4; ++i)
      af[i] = *(const bf16x8*)&As[PAR][wr*64 + i*16 + lm][lk*8];
    #pragma unroll
    for (int j = 0; j < FN; ++j)
      bfr[j] = *(const bf16x8*)&Bs[PAR][wc*FN*16 + j*16 + lm][lk*8];
    #pragma unroll
    for (int i = 0; i < 4; ++i)
      #pragma unroll
      for (int j = 0; j < FN; ++j)
        acc[i][j] = __builtin_amdgcn_mfma_f32_16x16x32_bf16(
            af[i], bfr[j], acc[i][j], 0, 0, 0);
  };

  loadA(ra0, 0); loadB(0); loadA(ra1, 32);
  for (int tt = 0; tt < 8; ++tt) {
    phase(2*tt,     std::integral_constant<int,0>{}, ra0);
    phase(2*tt + 1, std::integral_constant<int,1>{}, ra1);
  }

  // epilogue: C/D layout col=lane&15, row=(lane>>4)*4+r
  #pragma unroll
  for (int i = 0; i < 4; ++i) {
    #pragma unroll
    for (int j = 0; j < FN; ++j) {
      #pragma unroll
      for (int r = 0; r < 4; ++r) {
        int mg = mblk + wr*64 + i*16 + lk*4 + r;
        int ng = nblk + wc*FN*16 + j*16 + lm;
        Y[(size_t)mg * NOUT + ng] = (OutT)acc[i][j][r];
      }
    }
  }
}

// ---------------------------------------------------------------------------
// proj_all: one launch for v,q,k so blocks co-reside (latency hiding).
// grid (6, 256) x 512thr: x = role (0..3: v n-col; 4: q; 5: k), y = m-block.
// ---------------------------------------------------------------------------
__global__ __launch_bounds__(512) void proj_all_kernel(
    const float* __restrict__ x3, const float* __restrict__ Wv,
    const float* __restrict__ bv, __bf16* __restrict__ v_t,
    const float* __restrict__ x1, const float* __restrict__ Wq,
    const float* __restrict__ bq, __bf16* __restrict__ q_t,
    const float* __restrict__ x2, const float* __restrict__ Wk,
    const float* __restrict__ bk, __bf16* __restrict__ k_t)
{
  __shared__ __align__(16) __bf16 AsPool[2*128*40];   // 20480 B
  __shared__ __align__(16) __bf16 BsPool[2*128*40];   // 20480 B
  const int role = blockIdx.x;
  const int mblk = blockIdx.y * 128;
  if (role < 4) {
    proj_body<2, CH, __bf16>(AsPool, BsPool, x3, Wv, bv, v_t, mblk, role*128);
  } else if (role == 4) {
    proj_body<1, CQ, __bf16>(AsPool, BsPool, x1, Wq, bq, q_t, mblk, 0);
  } else {
    proj_body<1, CQ, __bf16>(AsPool, BsPool, x2, Wk, bk, k_t, mblk, 0);
  }
}

// ---------------------------------------------------------------------------
// energyH: eH[b,h,w,g] = (h<L && g<L) ? q.k : 0, -inf diag. grid (W,B), 256.
// ---------------------------------------------------------------------------
__global__ __launch_bounds__(256) void energyH_kernel(
    const __bf16* __restrict__ qt, const __bf16* __restrict__ kt,
    float* __restrict__ eH, const int* __restrict__ len_p)
{
  const int tid = threadIdx.x;
  const int w = blockIdx.x, b = blockIdx.y;
  int L = *len_p; L = L < 0 ? 0 : (L > 64 ? 64 : L);
  __shared__ float Qs[64][68];
  __shared__ float Ks[64][68];
  {
    const int c = tid & 63, hg = tid >> 6;
    const __bf16* qb = qt + ((size_t)b * PP + w) * CQ + c;
    const __bf16* kb = kt + ((size_t)b * PP + w) * CQ + c;
    #pragma unroll
    for (int r = 0; r < 16; ++r) {
      int h = hg*16 + r;
      Qs[h][c] = (float)qb[(size_t)h * WW * CQ];
      Ks[h][c] = (float)kb[(size_t)h * WW * CQ];
    }
  }
  __syncthreads();
  const int g  = tid & 63;
  const int wg = tid >> 6;
  float kreg[64];
  #pragma unroll
  for (int c = 0; c < 64; ++c) kreg[c] = (c < L) ? Ks[g][c] : 0.0f;
  const bool gok = (g < L);
  float* ab = eH + (((size_t)b * HH) * WW + w) * 64 + g;
  for (int r = 0; r < 16; ++r) {
    int h = wg*16 + r;
    float e = 0.0f;
    #pragma unroll
    for (int c4 = 0; c4 < 16; ++c4) {
      float4 q4 = *(const float4*)&Qs[h][4*c4];
      e += q4.x*kreg[4*c4+0] + q4.y*kreg[4*c4+1]
         + q4.z*kreg[4*c4+2] + q4.w*kreg[4*c4+3];
    }
    e = (gok && h < L) ? e : 0.0f;
    if (g == h) e = -INFINITY;
    ab[(size_t)h * WW * 64] = e;
  }
}

// ---------------------------------------------------------------------------
// energyW + softmax over [eH | eW]; writes bf16 probs to attHb / attWb.
// grid (H, B), block 256.
// ---------------------------------------------------------------------------
__global__ __launch_bounds__(256) void energyW_softmax_kernel(
    const __bf16* __restrict__ qt, const __bf16* __restrict__ kt,
    const float* __restrict__ eH,
    __bf16* __restrict__ attHb, __bf16* __restrict__ attWb,
    const int* __restrict__ len_p)
{
  const int tid = threadIdx.x;
  const int h = blockIdx.x, b = blockIdx.y;
  int L = *len_p; L = L < 0 ? 0 : (L > 64 ? 64 : L);
  __shared__ float Qs[64][68];
  __shared__ float Ks[64][68];
  {
    const int c = tid & 63, wg2 = tid >> 6;
    const __bf16* qb = qt + ((size_t)b * PP + (size_t)h * WW) * CQ + c;
    const __bf16* kb = kt + ((size_t)b * PP + (size_t)h * WW) * CQ + c;
    #pragma unroll
    for (int r = 0; r < 16; ++r) {
      int w = wg2*16 + r;
      Qs[w][c] = (float)qb[(size_t)w * CQ];
      Ks[w][c] = (float)kb[(size_t)w * CQ];
    }
  }
  __syncthreads();
  const int g  = tid & 63;
  const int wg = tid >> 6;
  float kreg[64];
  #pragma unroll
  for (int c = 0; c < 64; ++c) kreg[c] = (c < L) ? Ks[g][c] : 0.0f;
  const bool gok = (g < L);
  const float* ehb = eH + (((size_t)b * HH + h) * WW) * 64 + g;
  __bf16* ahb = attHb + (((size_t)b * HH + h) * WW) * 64 + g;
  __bf16* awb = attWb + (((size_t)b * HH + h) * WW) * 64 + g;
  for (int r = 0; r < 16; ++r) {
    int w = wg*16 + r;
    float e = 0.0f;
    #pragma unroll
    for (int c4 = 0; c4 < 16; ++c4) {
      float4 q4 = *(const float4*)&Qs[w][4*c4];
      e += q4.x*kreg[4*c4+0] + q4.y*kreg[4*c4+1]
         + q4.z*kreg[4*c4+2] + q4.w*kreg[4*c4+3];
    }
    e = (gok && w < L) ? e : 0.0f;
    float eh = ehb[(size_t)w * 64];
    float m = fmaxf(e, eh);
    #pragma unroll
    for (int d = 32; d > 0; d >>= 1) m = fmaxf(m, __shfl_xor(m, d, 64));
    float pe = __expf(e  - m);
    float ph = __expf(eh - m);
    float s = pe + ph;
    #pragma unroll
    for (int d = 32; d > 0; d >>= 1) s += __shfl_xor(s, d, 64);
    float inv = 1.0f / s;
    ahb[(size_t)w * 64] = (__bf16)(ph * inv);
    awb[(size_t)w * 64] = (__bf16)(pe * inv);
  }
}

// ---------------------------------------------------------------------------
// V staging into 16x16-subtiled LDS (64j x 64c tile) with j-permutation so
// ds_read_b64_tr_b16 (lane addr = subtile_base + 8*l) yields B-fragments:
//   s=j>>5, p=(j>>2)&1, t=((j&31)>>3)*4+(j&3), cb=c>>4
//   entry offset = ((s*2+p)*4 + cb)*256 + t*16 + (c&15)   [bf16 entries]
// ---------------------------------------------------------------------------
__device__ __forceinline__ int vsub64_off(int j, int c) {
  int s  = j >> 5;
  int p  = (j >> 2) & 1;
  int t  = ((j & 31) >> 3) * 4 + (j & 3);
  return ((s*2 + p)*4 + (c >> 4))*256 + t*16 + (c & 15);
}

// ---------------------------------------------------------------------------
// outH (MFMA): per (b,w,cq): oH[b,h,w, cq*64+c'] = sum_j attH[h,j]*v[j*64+w,c]
// grid (W, 8, B), block 256 (4 waves; wave wv owns h rows wv*16..+15).
// ---------------------------------------------------------------------------
__global__ __launch_bounds__(256) void outH_mfma_kernel(
    const __bf16* __restrict__ attHb, const __bf16* __restrict__ vt,
    __bf16* __restrict__ oH)
{
  const int tid = threadIdx.x;
  const int w = blockIdx.x, cq = blockIdx.y, b = blockIdx.z;
  const int l = tid & 63, wv = tid >> 6;
  const int lm = l & 15, lk = l >> 4;

  __shared__ __align__(16) __bf16 Bs[4096];

  #pragma unroll
  for (int i = 0; i < 2; ++i) {
    int j  = i*32 + (tid >> 3);
    int c0 = (tid & 7) * 8;
    bf16x8 v8 = *(const bf16x8*)(vt + ((size_t)b*PP + (size_t)j*WW + w)*CH + cq*64 + c0);
    *(bf16x8*)&Bs[vsub64_off(j, c0)] = v8;
  }

  const int hrow = wv*16 + lm;
  const __bf16* ab = attHb + (((size_t)b*HH + hrow)*WW + w)*64;
  bf16x8 af[2];
  af[0] = *(const bf16x8*)(ab + lk*8);
  af[1] = *(const bf16x8*)(ab + 32 + lk*8);
  __syncthreads();

  const unsigned bs_base = lds_off(&Bs[0]);
  f32x4 acc[4];
  #pragma unroll
  for (int f = 0; f < 4; ++f) acc[f] = (f32x4){0.f,0.f,0.f,0.f};
  #pragma unroll
  for (int s = 0; s < 2; ++s) {
    bf16x8 bfr[4];
    #pragma unroll
    for (int f = 0; f < 4; ++f) {
      unsigned base = bs_base + (unsigned)((((s*2)*4 + f)*512)) + (unsigned)(l*8);
      bf16x4 t0 = ds_tr16(base);
      bf16x4 t1 = ds_tr16(base + 2048);   // p=1 block
      bfr[f] = __builtin_shufflevector(t0, t1, 0,1,2,3,4,5,6,7);
    }
    asm volatile("s_waitcnt lgkmcnt(0)");
    __builtin_amdgcn_sched_barrier(0);
    #pragma unroll
    for (int f = 0; f < 4; ++f)
      acc[f] = __builtin_amdgcn_mfma_f32_16x16x32_bf16(af[s], bfr[f], acc[f], 0,0,0);
  }
  __bf16* ob = oH + (((size_t)b * HH) * WW + w) * CH + cq*64;
  #pragma unroll
  for (int f = 0; f < 4; ++f) {
    #pragma unroll
    for (int r = 0; r < 4; ++r) {
      int h = wv*16 + lk*4 + r;
      ob[(size_t)h * WW * CH + f*16 + lm] = (__bf16)acc[f][r];
    }
  }
}

// ---------------------------------------------------------------------------
// outW (MFMA) + final: per (b,h,cq): out = gamma*(outW + oH) + x1
// grid (H, 8, B), block 256. oH + x1 prefetched into registers at start;
// LDS union: Bs (8KB) then Sc [64][69] f32 (17.7KB).
// ---------------------------------------------------------------------------
__global__ __launch_bounds__(256) void outW_final_kernel(
    const __bf16* __restrict__ attWb, const __bf16* __restrict__ vt,
    const __bf16* __restrict__ oH,
    const float* __restrict__ x1, const float* __restrict__ gamma_p,
    float* __restrict__ out)
{
  const int tid = threadIdx.x;
  const int h = blockIdx.x, cq = blockIdx.y, b = blockIdx.z;
  const int l = tid & 63, wv = tid >> 6;
  const int lm = l & 15, lk = l >> 4;
  const float gamma = *gamma_p;

  __shared__ __align__(16) char smem[64*69*4];   // 17664 B
  __bf16* Bs = (__bf16*)smem;                    // 4096 entries (8 KB)
  typedef float ScRow[69];
  ScRow* Sc = (ScRow*)smem;                      // [64][69] f32

  #pragma unroll
  for (int i = 0; i < 2; ++i) {
    int j  = i*32 + (tid >> 3);
    int c0 = (tid & 7) * 8;
    bf16x8 v8 = *(const bf16x8*)(vt + ((size_t)b*PP + (size_t)h*WW + j)*CH + cq*64 + c0);
    *(bf16x8*)&Bs[vsub64_off(j, c0)] = v8;
  }

  const int wrow = wv*16 + lm;
  const __bf16* ab = attWb + (((size_t)b*HH + h)*WW + wrow)*64;
  bf16x8 af[2];
  af[0] = *(const bf16x8*)(ab + lk*8);
  af[1] = *(const bf16x8*)(ab + 32 + lk*8);

  // final-pass layout prefetch (T14): lane -> (w = wl, c rows ci = cg*16+r2)
  const int wl = tid & 63, cg = tid >> 6;
  const __bf16* ohb = oH + ((((size_t)b*HH + h) * WW) + wl) * CH + cq*64 + cg*16;
  bf16x8 ohr[2];
  ohr[0] = *(const bf16x8*)(ohb);
  ohr[1] = *(const bf16x8*)(ohb + 8);
  float x1r[16];
  {
    const float* x1b = x1 + ((size_t)b*CH + cq*64 + cg*16)*PP + (size_t)h*WW + wl;
    #pragma unroll
    for (int r2 = 0; r2 < 16; ++r2)
      x1r[r2] = x1b[(size_t)r2 * PP];
  }
  __syncthreads();

  const unsigned bs_base = lds_off(&Bs[0]);
  f32x4 acc[4];
  #pragma unroll
  for (int f = 0; f < 4; ++f) acc[f] = (f32x4){0.f,0.f,0.f,0.f};
  #pragma unroll
  for (int s = 0; s < 2; ++s) {
    bf16x8 bfr[4];
    #pragma unroll
    for (int f = 0; f < 4; ++f) {
      unsigned base = bs_base + (unsigned)((((s*2)*4 + f)*512)) + (unsigned)(l*8);
      bf16x4 t0 = ds_tr16(base);
      bf16x4 t1 = ds_tr16(base + 2048);
      bfr[f] = __builtin_shufflevector(t0, t1, 0,1,2,3,4,5,6,7);
    }
    asm volatile("s_waitcnt lgkmcnt(0)");
    __builtin_amdgcn_sched_barrier(0);
    #pragma unroll
    for (int f = 0; f < 4; ++f)
      acc[f] = __builtin_amdgcn_mfma_f32_16x16x32_bf16(af[s], bfr[f], acc[f], 0,0,0);
  }

  __syncthreads();   // all tr16 reads of Bs done (Sc aliases Bs)
  #pragma unroll
  for (int f = 0; f < 4; ++f) {
    #pragma unroll
    for (int r = 0; r < 4; ++r)
      Sc[wv*16 + lk*4 + r][f*16 + lm] = acc[f][r];
  }
  __syncthreads();
  {
    float* obp = out + ((size_t)b*CH + cq*64 + cg*16)*PP + (size_t)h*WW + wl;
    #pragma unroll
    for (int r2 = 0; r2 < 16; ++r2) {
      float oh = (float)ohr[r2 >> 3][r2 & 7];
      obp[(size_t)r2 * PP] = gamma * (Sc[wl][cg*16 + r2] + oh) + x1r[r2];
    }
  }
}

// ---------------------------------------------------------------------------
extern "C" void kernel_launch(void* const* d_in, const int* in_sizes, int n_in,
                              void* d_out, int out_size, void* d_ws, size_t ws_size,
                              hipStream_t stream)
{
  const float* x1 = (const float*)d_in[0];
  const float* x2 = (const float*)d_in[1];
  const float* x3 = (const float*)d_in[2];
  const float* Wq = (const float*)d_in[3];
  const float* bq = (const float*)d_in[4];
  const float* Wk = (const float*)d_in[5];
  const float* bk = (const float*)d_in[6];
  const float* Wv = (const float*)d_in[7];
  const float* bv = (const float*)d_in[8];
  const float* gamma = (const float*)d_in[9];
  const int*   len   = (const int*)d_in[10];
  float* out = (float*)d_out;

  // workspace layout (<= 96 MiB):
  __bf16* q_t   = (__bf16*)d_ws;                          // (B,P,64)   bf16  4 MiB
  __bf16* k_t   = q_t + (size_t)BB * PP * CQ;             // (B,P,64)   bf16  4 MiB
  float*  eH    = (float*)(k_t + (size_t)BB * PP * CQ);   // (B,H,W,64) f32   8 MiB
  __bf16* attHb = (__bf16*)(eH + (size_t)BB * PP * 64);   // (B,H,W,64) bf16  4 MiB
  __bf16* attWb = attHb + (size_t)BB * PP * 64;           // (B,H,W,64) bf16  4 MiB
  __bf16* v_t   = attWb + (size_t)BB * PP * 64;           // (B,P,512)  bf16 32 MiB
  __bf16* oH    = v_t + (size_t)BB * PP * CH;             // (B,H,W,512)bf16 32 MiB

  // all projections in ONE launch (512 thr, 8 waves/block): roles interleave
  // (x fastest) for co-residency; v = 4 n-cols of 128, q/k = BN=64 GEMMs.
  proj_all_kernel<<<dim3(6, BB*PP/128), dim3(512), 0, stream>>>(
      x3, Wv, bv, v_t,  x1, Wq, bq, q_t,  x2, Wk, bk, k_t);

  dim3 blk(256);
  energyH_kernel<<<dim3(WW, BB), blk, 0, stream>>>(q_t, k_t, eH, len);
  energyW_softmax_kernel<<<dim3(HH, BB), blk, 0, stream>>>(q_t, k_t, eH, attHb, attWb, len);
  outH_mfma_kernel<<<dim3(WW, 8, BB), blk, 0, stream>>>(attHb, v_t, oH);
  outW_final_kernel<<<dim3(HH, 8, BB), blk, 0, stream>>>(attWb, v_t, oH, x1, gamma, out);
}

// Round 12
// 147.825 us; speedup vs baseline: 1.1484x; 1.1484x over previous
//
#include <hip/hip_runtime.h>
#include <math.h>
#include <type_traits>

#define CH 512
#define CQ 64
#define HH 64
#define WW 64
#define PP (HH*WW)   // 4096
#define BB 8

typedef __bf16 bf16x8 __attribute__((ext_vector_type(8)));
typedef __bf16 bf16x4 __attribute__((ext_vector_type(4)));
typedef float  f32x4  __attribute__((ext_vector_type(4)));

// ---- LDS helpers (inline asm; keep asm ds ops and compiler ds ops in
// ---- disjoint regions, one lgkmcnt(0)+sched_barrier(0) before MFMAs) ----
__device__ __forceinline__ unsigned lds_off(const void* p) {
  return (unsigned)(size_t)(__attribute__((address_space(3))) const void*)p;
}
__device__ __forceinline__ bf16x4 ds_tr16(unsigned addr) {
  bf16x4 r;
  asm volatile("ds_read_b64_tr_b16 %0, %1" : "=v"(r) : "v"(addr));
  return r;
}

// ---------------------------------------------------------------------------
// proj_body (R9-proven): one 128xBN tile of Y[m,o] = sum_c X[b,c,p]*W[o,c]+b.
// 256 thr, 2x2 wave grid, wave tile 64x(FN*16); dbuf LDS; static depth-2
// A prefetch (named ra0/ra1, phase-unrolled; rule-#20 safe). Plain bf16.
// ---------------------------------------------------------------------------
template<int FM, int FN, int NOUT, typename OutT>
__device__ __forceinline__ void proj_body(
    __bf16* AsBase, __bf16* BsBase,
    const float* __restrict__ X, const float* __restrict__ W,
    const float* __restrict__ bias, OutT* __restrict__ Y,
    int mblk, int nblk)
{
  constexpr int BM = 32 * FM;
  constexpr int BN = 32 * FN;
  constexpr int GA = BM / 64;
  constexpr int GB = BN / 64;
  typedef __bf16 (*TileA)[BM][40];
  typedef __bf16 (*TileB)[BN][40];
  TileA As = (TileA)AsBase;   // [2][BM][40]
  TileB Bs = (TileB)BsBase;   // [2][BN][40]

  const int tid = threadIdx.x;
  const int b     = mblk >> 12;             // BM divides 4096
  const int pbase = mblk & 4095;
  const float* Xb = X + (size_t)b * CH * PP;

  const int l  = tid & 63;
  const int wv = tid >> 6;
  const int wr = wv >> 1, wc = wv & 1;
  const int lm = l & 15, lk = l >> 4;

  int ma[GA], ka[GA];
  #pragma unroll
  for (int gi = 0; gi < GA; ++gi) {
    int g = tid + gi * 256;
    ma[gi] = g % BM;
    ka[gi] = (g / BM) * 8;
  }
  int nb_[GB], kb_[GB];
  #pragma unroll
  for (int gi = 0; gi < GB; ++gi) {
    int g = tid + gi * 256;
    nb_[gi] = g >> 2;
    kb_[gi] = (g & 3) * 8;
  }

  float ra0[GA][8], ra1[GA][8];   // depth-2 A prefetch (named, static idx)
  float rb[GB][8];                // depth-1 B prefetch

  auto loadA = [&](float (&ra)[GA][8], int c0) {
    #pragma unroll
    for (int gi = 0; gi < GA; ++gi)
      #pragma unroll
      for (int jj = 0; jj < 8; ++jj)
        ra[gi][jj] = Xb[(size_t)(c0 + ka[gi] + jj) * PP + pbase + ma[gi]];
  };
  auto loadB = [&](int c0) {
    #pragma unroll
    for (int gi = 0; gi < GB; ++gi) {
      const float* src = W + (size_t)(nblk + nb_[gi]) * CH + c0 + kb_[gi];
      float4 f0 = *(const float4*)src;
      float4 f1 = *(const float4*)(src + 4);
      rb[gi][0]=f0.x; rb[gi][1]=f0.y; rb[gi][2]=f0.z; rb[gi][3]=f0.w;
      rb[gi][4]=f1.x; rb[gi][5]=f1.y; rb[gi][6]=f1.z; rb[gi][7]=f1.w;
    }
  };

  f32x4 acc[FM][FN];
  #pragma unroll
  for (int j = 0; j < FN; ++j) {
    float bvj = bias[nblk + wc*FN*16 + j*16 + lm];
    #pragma unroll
    for (int i = 0; i < FM; ++i) {
      acc[i][j][0] = bvj; acc[i][j][1] = bvj;
      acc[i][j][2] = bvj; acc[i][j][3] = bvj;
    }
  }

  auto phase = [&](int t, auto par_c, float (&ra)[GA][8]) {
    constexpr int PAR = decltype(par_c)::value;
    #pragma unroll
    for (int gi = 0; gi < GA; ++gi) {
      bf16x8 hv;
      #pragma unroll
      for (int jj = 0; jj < 8; ++jj) hv[jj] = (__bf16)ra[gi][jj];
      *(bf16x8*)&As[PAR][ma[gi]][ka[gi]] = hv;
    }
    #pragma unroll
    for (int gi = 0; gi < GB; ++gi) {
      bf16x8 hv;
      #pragma unroll
      for (int jj = 0; jj < 8; ++jj) hv[jj] = (__bf16)rb[gi][jj];
      *(bf16x8*)&Bs[PAR][nb_[gi]][kb_[gi]] = hv;
    }
    __syncthreads();
    if (t < 15) loadB((t+1)*32);
    if (t < 14) loadA(ra, (t+2)*32);
    bf16x8 af[FM], bfr[FN];
    #pragma unroll
    for (int i = 0; i < FM; ++i)
      af[i] = *(const bf16x8*)&As[PAR][wr*FM*16 + i*16 + lm][lk*8];
    #pragma unroll
    for (int j = 0; j < FN; ++j)
      bfr[j] = *(const bf16x8*)&Bs[PAR][wc*FN*16 + j*16 + lm][lk*8];
    #pragma unroll
    for (int i = 0; i < FM; ++i)
      #pragma unroll
      for (int j = 0; j < FN; ++j)
        acc[i][j] = __builtin_amdgcn_mfma_f32_16x16x32_bf16(
            af[i], bfr[j], acc[i][j], 0, 0, 0);
  };

  loadA(ra0, 0); loadB(0); loadA(ra1, 32);
  for (int tt = 0; tt < 8; ++tt) {
    phase(2*tt,     std::integral_constant<int,0>{}, ra0);
    phase(2*tt + 1, std::integral_constant<int,1>{}, ra1);
  }

  // epilogue: C/D layout col=lane&15, row=(lane>>4)*4+r
  #pragma unroll
  for (int i = 0; i < FM; ++i) {
    #pragma unroll
    for (int j = 0; j < FN; ++j) {
      #pragma unroll
      for (int r = 0; r < 4; ++r) {
        int mg = mblk + wr*FM*16 + i*16 + lk*4 + r;
        int ng = nblk + wc*FN*16 + j*16 + lm;
        Y[(size_t)mg * NOUT + ng] = (OutT)acc[i][j][r];
      }
    }
  }
}

// ---------------------------------------------------------------------------
// proj_all: one launch for v,q,k so blocks co-reside (latency hiding).
// grid (6, 256): x = role (0..3: v n-col; 4: q; 5: k), y = m-block (BM=128).
// ---------------------------------------------------------------------------
__global__ __launch_bounds__(256) void proj_all_kernel(
    const float* __restrict__ x3, const float* __restrict__ Wv,
    const float* __restrict__ bv, __bf16* __restrict__ v_t,
    const float* __restrict__ x1, const float* __restrict__ Wq,
    const float* __restrict__ bq, float* __restrict__ q_t,
    const float* __restrict__ x2, const float* __restrict__ Wk,
    const float* __restrict__ bk, float* __restrict__ k_t)
{
  __shared__ __align__(16) __bf16 AsPool[2*128*40];   // 20480 B
  __shared__ __align__(16) __bf16 BsPool[2*128*40];   // 20480 B
  const int role = blockIdx.x;
  const int mblk = blockIdx.y * 128;
  if (role < 4) {
    proj_body<4,4, CH, __bf16>(AsPool, BsPool, x3, Wv, bv, v_t, mblk, role*128);
  } else if (role == 4) {
    proj_body<4,2, CQ, float >(AsPool, BsPool, x1, Wq, bq, q_t, mblk, 0);
  } else {
    proj_body<4,2, CQ, float >(AsPool, BsPool, x2, Wk, bk, k_t, mblk, 0);
  }
}

// ---------------------------------------------------------------------------
// energyH: eH[b,h,w,g] = (h<L && g<L) ? q.k : 0, -inf diag.
// grid (W, B, 2): z selects 32 h-rows; 4 waves x 8 rows each.
// ---------------------------------------------------------------------------
__global__ __launch_bounds__(256) void energyH_kernel(
    const float* __restrict__ qt, const float* __restrict__ kt,
    float* __restrict__ eH, const int* __restrict__ len_p)
{
  const int tid = threadIdx.x;
  const int w = blockIdx.x, b = blockIdx.y, zz = blockIdx.z;
  int L = *len_p; L = L < 0 ? 0 : (L > 64 ? 64 : L);
  __shared__ float Qs[32][68];
  __shared__ float Ks[64][68];
  {
    const int c = tid & 63, grp = tid >> 6;
    const float* qb = qt + ((size_t)b * PP + w) * CQ + c;
    const float* kb = kt + ((size_t)b * PP + w) * CQ + c;
    #pragma unroll
    for (int r = 0; r < 8; ++r) {
      int hl = grp*8 + r;
      Qs[hl][c] = qb[(size_t)(zz*32 + hl) * WW * CQ];
    }
    #pragma unroll
    for (int r = 0; r < 16; ++r) {
      int hk = grp*16 + r;
      Ks[hk][c] = kb[(size_t)hk * WW * CQ];
    }
  }
  __syncthreads();
  const int g  = tid & 63;
  const int wg = tid >> 6;
  float kreg[64];
  #pragma unroll
  for (int c = 0; c < 64; ++c) kreg[c] = (c < L) ? Ks[g][c] : 0.0f;
  const bool gok = (g < L);
  float* ab = eH + (((size_t)b * HH) * WW + w) * 64 + g;
  for (int r = 0; r < 8; ++r) {
    int hl = wg*8 + r;
    int h  = zz*32 + hl;
    float e = 0.0f;
    #pragma unroll
    for (int c4 = 0; c4 < 16; ++c4) {
      float4 q4 = *(const float4*)&Qs[hl][4*c4];
      e += q4.x*kreg[4*c4+0] + q4.y*kreg[4*c4+1]
         + q4.z*kreg[4*c4+2] + q4.w*kreg[4*c4+3];
    }
    e = (gok && h < L) ? e : 0.0f;
    if (g == h) e = -INFINITY;
    ab[(size_t)h * WW * 64] = e;
  }
}

// ---------------------------------------------------------------------------
// energyW + softmax over [eH | eW]; writes bf16 probs to attHb / attWb.
// grid (H, B, 2): z selects 32 w-rows; 4 waves x 8 rows each.
// ---------------------------------------------------------------------------
__global__ __launch_bounds__(256) void energyW_softmax_kernel(
    const float* __restrict__ qt, const float* __restrict__ kt,
    const float* __restrict__ eH,
    __bf16* __restrict__ attHb, __bf16* __restrict__ attWb,
    const int* __restrict__ len_p)
{
  const int tid = threadIdx.x;
  const int h = blockIdx.x, b = blockIdx.y, zz = blockIdx.z;
  int L = *len_p; L = L < 0 ? 0 : (L > 64 ? 64 : L);
  __shared__ float Qs[32][68];
  __shared__ float Ks[64][68];
  {
    const int c = tid & 63, grp = tid >> 6;
    const float* qb = qt + ((size_t)b * PP + (size_t)h * WW) * CQ + c;
    const float* kb = kt + ((size_t)b * PP + (size_t)h * WW) * CQ + c;
    #pragma unroll
    for (int r = 0; r < 8; ++r) {
      int wl = grp*8 + r;
      Qs[wl][c] = qb[(size_t)(zz*32 + wl) * CQ];
    }
    #pragma unroll
    for (int r = 0; r < 16; ++r) {
      int wk = grp*16 + r;
      Ks[wk][c] = kb[(size_t)wk * CQ];
    }
  }
  __syncthreads();
  const int g  = tid & 63;
  const int wg = tid >> 6;
  float kreg[64];
  #pragma unroll
  for (int c = 0; c < 64; ++c) kreg[c] = (c < L) ? Ks[g][c] : 0.0f;
  const bool gok = (g < L);
  const float* ehb = eH + (((size_t)b * HH + h) * WW) * 64 + g;
  __bf16* ahb = attHb + (((size_t)b * HH + h) * WW) * 64 + g;
  __bf16* awb = attWb + (((size_t)b * HH + h) * WW) * 64 + g;
  for (int r = 0; r < 8; ++r) {
    int wl = wg*8 + r;
    int w  = zz*32 + wl;
    float e = 0.0f;
    #pragma unroll
    for (int c4 = 0; c4 < 16; ++c4) {
      float4 q4 = *(const float4*)&Qs[wl][4*c4];
      e += q4.x*kreg[4*c4+0] + q4.y*kreg[4*c4+1]
         + q4.z*kreg[4*c4+2] + q4.w*kreg[4*c4+3];
    }
    e = (gok && w < L) ? e : 0.0f;
    float eh = ehb[(size_t)w * 64];
    float m = fmaxf(e, eh);
    #pragma unroll
    for (int d = 32; d > 0; d >>= 1) m = fmaxf(m, __shfl_xor(m, d, 64));
    float pe = __expf(e  - m);
    float ph = __expf(eh - m);
    float s = pe + ph;
    #pragma unroll
    for (int d = 32; d > 0; d >>= 1) s += __shfl_xor(s, d, 64);
    float inv = 1.0f / s;
    ahb[(size_t)w * 64] = (__bf16)(ph * inv);
    awb[(size_t)w * 64] = (__bf16)(pe * inv);
  }
}

// ---------------------------------------------------------------------------
// V staging into 16x16-subtiled LDS (64j x 64c tile) with j-permutation so
// ds_read_b64_tr_b16 (lane addr = subtile_base + 8*l) yields B-fragments:
//   s=j>>5, p=(j>>2)&1, t=((j&31)>>3)*4+(j&3), cb=c>>4
//   entry offset = ((s*2+p)*4 + cb)*256 + t*16 + (c&15)   [bf16 entries]
// ---------------------------------------------------------------------------
__device__ __forceinline__ int vsub64_off(int j, int c) {
  int s  = j >> 5;
  int p  = (j >> 2) & 1;
  int t  = ((j & 31) >> 3) * 4 + (j & 3);
  return ((s*2 + p)*4 + (c >> 4))*256 + t*16 + (c & 15);
}

// ---------------------------------------------------------------------------
// outH (MFMA): per (b,w,cq): oH[b,h,w, cq*64+c'] = sum_j attH[h,j]*v[j*64+w,c]
// grid (W, 8, B), block 256 (4 waves; wave wv owns h rows wv*16..+15).
// ---------------------------------------------------------------------------
__global__ __launch_bounds__(256) void outH_mfma_kernel(
    const __bf16* __restrict__ attHb, const __bf16* __restrict__ vt,
    __bf16* __restrict__ oH)
{
  const int tid = threadIdx.x;
  const int w = blockIdx.x, cq = blockIdx.y, b = blockIdx.z;
  const int l = tid & 63, wv = tid >> 6;
  const int lm = l & 15, lk = l >> 4;

  __shared__ __align__(16) __bf16 Bs[4096];

  #pragma unroll
  for (int i = 0; i < 2; ++i) {
    int j  = i*32 + (tid >> 3);
    int c0 = (tid & 7) * 8;
    bf16x8 v8 = *(const bf16x8*)(vt + ((size_t)b*PP + (size_t)j*WW + w)*CH + cq*64 + c0);
    *(bf16x8*)&Bs[vsub64_off(j, c0)] = v8;
  }

  const int hrow = wv*16 + lm;
  const __bf16* ab = attHb + (((size_t)b*HH + hrow)*WW + w)*64;
  bf16x8 af[2];
  af[0] = *(const bf16x8*)(ab + lk*8);
  af[1] = *(const bf16x8*)(ab + 32 + lk*8);
  __syncthreads();

  const unsigned bs_base = lds_off(&Bs[0]);
  f32x4 acc[4];
  #pragma unroll
  for (int f = 0; f < 4; ++f) acc[f] = (f32x4){0.f,0.f,0.f,0.f};
  #pragma unroll
  for (int s = 0; s < 2; ++s) {
    bf16x8 bfr[4];
    #pragma unroll
    for (int f = 0; f < 4; ++f) {
      unsigned base = bs_base + (unsigned)((((s*2)*4 + f)*512)) + (unsigned)(l*8);
      bf16x4 t0 = ds_tr16(base);
      bf16x4 t1 = ds_tr16(base + 2048);   // p=1 block
      bfr[f] = __builtin_shufflevector(t0, t1, 0,1,2,3,4,5,6,7);
    }
    asm volatile("s_waitcnt lgkmcnt(0)");
    __builtin_amdgcn_sched_barrier(0);
    #pragma unroll
    for (int f = 0; f < 4; ++f)
      acc[f] = __builtin_amdgcn_mfma_f32_16x16x32_bf16(af[s], bfr[f], acc[f], 0,0,0);
  }
  __bf16* ob = oH + (((size_t)b * HH) * WW + w) * CH + cq*64;
  #pragma unroll
  for (int f = 0; f < 4; ++f) {
    #pragma unroll
    for (int r = 0; r < 4; ++r) {
      int h = wv*16 + lk*4 + r;
      ob[(size_t)h * WW * CH + f*16 + lm] = (__bf16)acc[f][r];
    }
  }
}

// ---------------------------------------------------------------------------
// outW (MFMA) + final: per (b,h,cq): out = gamma*(outW + oH) + x1
// grid (H, 8, B), block 256. oH + x1 prefetched into registers at start;
// LDS union: Bs (8KB) then Sc [64][69] f32 (17.7KB).
// ---------------------------------------------------------------------------
__global__ __launch_bounds__(256) void outW_final_kernel(
    const __bf16* __restrict__ attWb, const __bf16* __restrict__ vt,
    const __bf16* __restrict__ oH,
    const float* __restrict__ x1, const float* __restrict__ gamma_p,
    float* __restrict__ out)
{
  const int tid = threadIdx.x;
  const int h = blockIdx.x, cq = blockIdx.y, b = blockIdx.z;
  const int l = tid & 63, wv = tid >> 6;
  const int lm = l & 15, lk = l >> 4;
  const float gamma = *gamma_p;

  __shared__ __align__(16) char smem[64*69*4];   // 17664 B
  __bf16* Bs = (__bf16*)smem;                    // 4096 entries (8 KB)
  typedef float ScRow[69];
  ScRow* Sc = (ScRow*)smem;                      // [64][69] f32

  #pragma unroll
  for (int i = 0; i < 2; ++i) {
    int j  = i*32 + (tid >> 3);
    int c0 = (tid & 7) * 8;
    bf16x8 v8 = *(const bf16x8*)(vt + ((size_t)b*PP + (size_t)h*WW + j)*CH + cq*64 + c0);
    *(bf16x8*)&Bs[vsub64_off(j, c0)] = v8;
  }

  const int wrow = wv*16 + lm;
  const __bf16* ab = attWb + (((size_t)b*HH + h)*WW + wrow)*64;
  bf16x8 af[2];
  af[0] = *(const bf16x8*)(ab + lk*8);
  af[1] = *(const bf16x8*)(ab + 32 + lk*8);

  // final-pass layout prefetch (T14): lane -> (w = wl, c rows ci = cg*16+r2)
  const int wl = tid & 63, cg = tid >> 6;
  const __bf16* ohb = oH + ((((size_t)b*HH + h) * WW) + wl) * CH + cq*64 + cg*16;
  bf16x8 ohr[2];
  ohr[0] = *(const bf16x8*)(ohb);
  ohr[1] = *(const bf16x8*)(ohb + 8);
  float x1r[16];
  {
    const float* x1b = x1 + ((size_t)b*CH + cq*64 + cg*16)*PP + (size_t)h*WW + wl;
    #pragma unroll
    for (int r2 = 0; r2 < 16; ++r2)
      x1r[r2] = x1b[(size_t)r2 * PP];
  }
  __syncthreads();

  const unsigned bs_base = lds_off(&Bs[0]);
  f32x4 acc[4];
  #pragma unroll
  for (int f = 0; f < 4; ++f) acc[f] = (f32x4){0.f,0.f,0.f,0.f};
  #pragma unroll
  for (int s = 0; s < 2; ++s) {
    bf16x8 bfr[4];
    #pragma unroll
    for (int f = 0; f < 4; ++f) {
      unsigned base = bs_base + (unsigned)((((s*2)*4 + f)*512)) + (unsigned)(l*8);
      bf16x4 t0 = ds_tr16(base);
      bf16x4 t1 = ds_tr16(base + 2048);
      bfr[f] = __builtin_shufflevector(t0, t1, 0,1,2,3,4,5,6,7);
    }
    asm volatile("s_waitcnt lgkmcnt(0)");
    __builtin_amdgcn_sched_barrier(0);
    #pragma unroll
    for (int f = 0; f < 4; ++f)
      acc[f] = __builtin_amdgcn_mfma_f32_16x16x32_bf16(af[s], bfr[f], acc[f], 0,0,0);
  }

  __syncthreads();   // all tr16 reads of Bs done (Sc aliases Bs)
  #pragma unroll
  for (int f = 0; f < 4; ++f) {
    #pragma unroll
    for (int r = 0; r < 4; ++r)
      Sc[wv*16 + lk*4 + r][f*16 + lm] = acc[f][r];
  }
  __syncthreads();
  {
    float* obp = out + ((size_t)b*CH + cq*64 + cg*16)*PP + (size_t)h*WW + wl;
    #pragma unroll
    for (int r2 = 0; r2 < 16; ++r2) {
      float oh = (float)ohr[r2 >> 3][r2 & 7];
      obp[(size_t)r2 * PP] = gamma * (Sc[wl][cg*16 + r2] + oh) + x1r[r2];
    }
  }
}

// ---------------------------------------------------------------------------
extern "C" void kernel_launch(void* const* d_in, const int* in_sizes, int n_in,
                              void* d_out, int out_size, void* d_ws, size_t ws_size,
                              hipStream_t stream)
{
  const float* x1 = (const float*)d_in[0];
  const float* x2 = (const float*)d_in[1];
  const float* x3 = (const float*)d_in[2];
  const float* Wq = (const float*)d_in[3];
  const float* bq = (const float*)d_in[4];
  const float* Wk = (const float*)d_in[5];
  const float* bk = (const float*)d_in[6];
  const float* Wv = (const float*)d_in[7];
  const float* bv = (const float*)d_in[8];
  const float* gamma = (const float*)d_in[9];
  const int*   len   = (const int*)d_in[10];
  float* out = (float*)d_out;

  // workspace layout (96 MiB total):
  float*  q_t   = (float*)d_ws;                           // (B,P,64)   f32   8 MiB
  float*  k_t   = q_t + (size_t)BB * PP * CQ;             // (B,P,64)   f32   8 MiB
  float*  eH    = k_t + (size_t)BB * PP * CQ;             // (B,H,W,64) f32   8 MiB
  __bf16* attHb = (__bf16*)(eH + (size_t)BB * PP * 64);   // (B,H,W,64) bf16  4 MiB
  __bf16* attWb = attHb + (size_t)BB * PP * 64;           // (B,H,W,64) bf16  4 MiB
  __bf16* v_t   = attWb + (size_t)BB * PP * 64;           // (B,P,512)  bf16 32 MiB
  __bf16* oH    = v_t + (size_t)BB * PP * CH;             // (B,H,W,512)bf16 32 MiB

  dim3 blk(256);
  // all projections in ONE launch (R9-proven): roles interleave (x fastest)
  // for co-residency; v = 4 n-cols of 128, q/k = BN=64 plain-bf16 GEMMs.
  proj_all_kernel<<<dim3(6, BB*PP/128), blk, 0, stream>>>(
      x3, Wv, bv, v_t,  x1, Wq, bq, q_t,  x2, Wk, bk, k_t);

  energyH_kernel<<<dim3(WW, BB, 2), blk, 0, stream>>>(q_t, k_t, eH, len);
  energyW_softmax_kernel<<<dim3(HH, BB, 2), blk, 0, stream>>>(q_t, k_t, eH, attHb, attWb, len);
  outH_mfma_kernel<<<dim3(WW, 8, BB), blk, 0, stream>>>(attHb, v_t, oH);
  outW_final_kernel<<<dim3(HH, 8, BB), blk, 0, stream>>>(attWb, v_t, oH, x1, gamma, out);
}

// Round 13
// 144.230 us; speedup vs baseline: 1.1770x; 1.0249x over previous
//
#include <hip/hip_runtime.h>
#include <math.h>
#include <type_traits>

#define CH 512
#define CQ 64
#define HH 64
#define WW 64
#define PP (HH*WW)   // 4096
#define BB 8

typedef __bf16 bf16x8 __attribute__((ext_vector_type(8)));
typedef __bf16 bf16x4 __attribute__((ext_vector_type(4)));
typedef float  f32x4  __attribute__((ext_vector_type(4)));

// ---- LDS helpers (inline asm; keep asm ds ops and compiler ds ops in
// ---- disjoint regions, one lgkmcnt(0)+sched_barrier(0) before MFMAs) ----
__device__ __forceinline__ unsigned lds_off(const void* p) {
  return (unsigned)(size_t)(__attribute__((address_space(3))) const void*)p;
}
__device__ __forceinline__ bf16x4 ds_tr16(unsigned addr) {
  bf16x4 r;
  asm volatile("ds_read_b64_tr_b16 %0, %1" : "=v"(r) : "v"(addr));
  return r;
}

// ---------------------------------------------------------------------------
// proj_body: one 128xBN tile of Y[m,o] = sum_c X[b,c,p]*W[o,c] + bias[o].
// 256 thr, 2x2 waves, wave tile 64x(FN*16); dbuf LDS; static depth-2 A
// prefetch. A loads: 4x float4 per thread (4p x 4c block, in-reg transpose),
// staged into a 16B-XOR-swizzled [m][k] tile (unit' = unit ^ ((m>>2)&3));
// frag reads apply the same XOR (reduces to lk^(lm>>2), const per thread).
// ---------------------------------------------------------------------------
template<int FM, int FN, int NOUT, typename OutT>
__device__ __forceinline__ void proj_body(
    __bf16* AsBase, __bf16* BsBase,
    const float* __restrict__ X, const float* __restrict__ W,
    const float* __restrict__ bias, OutT* __restrict__ Y,
    int mblk, int nblk)
{
  constexpr int BM = 32 * FM;   // 128
  constexpr int BN = 32 * FN;
  constexpr int GB = BN / 64;
  typedef __bf16 (*TileA)[BM][40];
  typedef __bf16 (*TileB)[BN][40];
  TileA As = (TileA)AsBase;   // [2][128][40]
  TileB Bs = (TileB)BsBase;   // [2][BN][40]

  const int tid = threadIdx.x;
  const int b     = mblk >> 12;             // BM divides 4096
  const int pbase = mblk & 4095;
  const float* Xb = X + (size_t)b * CH * PP;

  const int l  = tid & 63;
  const int wv = tid >> 6;
  const int wr = wv >> 1, wc = wv & 1;
  const int lm = l & 15, lk = l >> 4;

  // A-thread geometry: 4 consecutive p, 4 consecutive c
  const int p4    = (tid & 31) * 4;
  const int cbase = (tid >> 5) * 4;
  const int uA    = ((cbase >> 3) ^ (tid & 3)) * 8 + ((cbase >> 2) & 1) * 4;
  // frag-read k offset (XOR-swizzled, const per thread)
  const int kfr   = (lk ^ (lm >> 2)) * 8;

  int nb_[GB], kb_[GB];
  #pragma unroll
  for (int gi = 0; gi < GB; ++gi) {
    int g = tid + gi * 256;
    nb_[gi] = g >> 2;
    kb_[gi] = (g & 3) * 8;
  }

  float ra0[16], ra1[16];   // depth-2 A prefetch: [gi][pp] flattened
  float rb[GB][8];          // depth-1 B prefetch

  auto loadA = [&](float (&ra)[16], int c0) {
    #pragma unroll
    for (int gi = 0; gi < 4; ++gi)
      *(float4*)&ra[gi*4] =
          *(const float4*)(Xb + (size_t)(c0 + cbase + gi) * PP + pbase + p4);
  };
  auto loadB = [&](int c0) {
    #pragma unroll
    for (int gi = 0; gi < GB; ++gi) {
      const float* src = W + (size_t)(nblk + nb_[gi]) * CH + c0 + kb_[gi];
      float4 f0 = *(const float4*)src;
      float4 f1 = *(const float4*)(src + 4);
      rb[gi][0]=f0.x; rb[gi][1]=f0.y; rb[gi][2]=f0.z; rb[gi][3]=f0.w;
      rb[gi][4]=f1.x; rb[gi][5]=f1.y; rb[gi][6]=f1.z; rb[gi][7]=f1.w;
    }
  };

  f32x4 acc[FM][FN];
  #pragma unroll
  for (int j = 0; j < FN; ++j) {
    float bvj = bias[nblk + wc*FN*16 + j*16 + lm];
    #pragma unroll
    for (int i = 0; i < FM; ++i) {
      acc[i][j][0] = bvj; acc[i][j][1] = bvj;
      acc[i][j][2] = bvj; acc[i][j][3] = bvj;
    }
  }

  auto phase = [&](int t, auto par_c, float (&ra)[16]) {
    constexpr int PAR = decltype(par_c)::value;
    // stage A: in-register 4x4 transpose, swizzled bf16x4 writes
    #pragma unroll
    for (int pp = 0; pp < 4; ++pp) {
      bf16x4 hv;
      hv[0] = (__bf16)ra[0*4 + pp];
      hv[1] = (__bf16)ra[1*4 + pp];
      hv[2] = (__bf16)ra[2*4 + pp];
      hv[3] = (__bf16)ra[3*4 + pp];
      *(bf16x4*)&As[PAR][p4 + pp][uA] = hv;
    }
    // stage B (unswizzled [n][k])
    #pragma unroll
    for (int gi = 0; gi < GB; ++gi) {
      bf16x8 hv;
      #pragma unroll
      for (int jj = 0; jj < 8; ++jj) hv[jj] = (__bf16)rb[gi][jj];
      *(bf16x8*)&Bs[PAR][nb_[gi]][kb_[gi]] = hv;
    }
    __syncthreads();
    if (t < 15) loadB((t+1)*32);
    if (t < 14) loadA(ra, (t+2)*32);
    bf16x8 af[FM], bfr[FN];
    #pragma unroll
    for (int i = 0; i < FM; ++i)
      af[i] = *(const bf16x8*)&As[PAR][wr*FM*16 + i*16 + lm][kfr];
    #pragma unroll
    for (int j = 0; j < FN; ++j)
      bfr[j] = *(const bf16x8*)&Bs[PAR][wc*FN*16 + j*16 + lm][lk*8];
    #pragma unroll
    for (int i = 0; i < FM; ++i)
      #pragma unroll
      for (int j = 0; j < FN; ++j)
        acc[i][j] = __builtin_amdgcn_mfma_f32_16x16x32_bf16(
            af[i], bfr[j], acc[i][j], 0, 0, 0);
  };

  loadA(ra0, 0); loadB(0); loadA(ra1, 32);
  for (int tt = 0; tt < 8; ++tt) {
    phase(2*tt,     std::integral_constant<int,0>{}, ra0);
    phase(2*tt + 1, std::integral_constant<int,1>{}, ra1);
  }

  // epilogue: C/D layout col=lane&15, row=(lane>>4)*4+r
  #pragma unroll
  for (int i = 0; i < FM; ++i) {
    #pragma unroll
    for (int j = 0; j < FN; ++j) {
      #pragma unroll
      for (int r = 0; r < 4; ++r) {
        int mg = mblk + wr*FM*16 + i*16 + lk*4 + r;
        int ng = nblk + wc*FN*16 + j*16 + lm;
        Y[(size_t)mg * NOUT + ng] = (OutT)acc[i][j][r];
      }
    }
  }
}

// ---------------------------------------------------------------------------
// proj_all: one launch for v,q,k so blocks co-reside (latency hiding).
// grid (256, 6): x = m-block, y = role (0..3: v n-col; 4: q; 5: k).
// linear id = x + 256*y -> id%8 = mblk%8, so all 6 roles of an m-block land
// on the SAME XCD (shared x-panel reads become L2 hits).
// ---------------------------------------------------------------------------
__global__ __launch_bounds__(256) void proj_all_kernel(
    const float* __restrict__ x3, const float* __restrict__ Wv,
    const float* __restrict__ bv, __bf16* __restrict__ v_t,
    const float* __restrict__ x1, const float* __restrict__ Wq,
    const float* __restrict__ bq, float* __restrict__ q_t,
    const float* __restrict__ x2, const float* __restrict__ Wk,
    const float* __restrict__ bk, float* __restrict__ k_t)
{
  __shared__ __align__(16) __bf16 AsPool[2*128*40];   // 20480 B
  __shared__ __align__(16) __bf16 BsPool[2*128*40];   // 20480 B
  const int role = blockIdx.y;
  const int mblk = blockIdx.x * 128;
  if (role < 4) {
    proj_body<4,4, CH, __bf16>(AsPool, BsPool, x3, Wv, bv, v_t, mblk, role*128);
  } else if (role == 4) {
    proj_body<4,2, CQ, float >(AsPool, BsPool, x1, Wq, bq, q_t, mblk, 0);
  } else {
    proj_body<4,2, CQ, float >(AsPool, BsPool, x2, Wk, bk, k_t, mblk, 0);
  }
}

// ---------------------------------------------------------------------------
// energyH: eH[b,h,w,g] = (h<L && g<L) ? q.k : 0, -inf diag.
// grid (W, B, 2): z selects 32 h-rows; 4 waves x 8 rows each.
// ---------------------------------------------------------------------------
__global__ __launch_bounds__(256) void energyH_kernel(
    const float* __restrict__ qt, const float* __restrict__ kt,
    float* __restrict__ eH, const int* __restrict__ len_p)
{
  const int tid = threadIdx.x;
  const int w = blockIdx.x, b = blockIdx.y, zz = blockIdx.z;
  int L = *len_p; L = L < 0 ? 0 : (L > 64 ? 64 : L);
  __shared__ float Qs[32][68];
  __shared__ float Ks[64][68];
  {
    const int c = tid & 63, grp = tid >> 6;
    const float* qb = qt + ((size_t)b * PP + w) * CQ + c;
    const float* kb = kt + ((size_t)b * PP + w) * CQ + c;
    #pragma unroll
    for (int r = 0; r < 8; ++r) {
      int hl = grp*8 + r;
      Qs[hl][c] = qb[(size_t)(zz*32 + hl) * WW * CQ];
    }
    #pragma unroll
    for (int r = 0; r < 16; ++r) {
      int hk = grp*16 + r;
      Ks[hk][c] = kb[(size_t)hk * WW * CQ];
    }
  }
  __syncthreads();
  const int g  = tid & 63;
  const int wg = tid >> 6;
  float kreg[64];
  #pragma unroll
  for (int c = 0; c < 64; ++c) kreg[c] = (c < L) ? Ks[g][c] : 0.0f;
  const bool gok = (g < L);
  float* ab = eH + (((size_t)b * HH) * WW + w) * 64 + g;
  for (int r = 0; r < 8; ++r) {
    int hl = wg*8 + r;
    int h  = zz*32 + hl;
    float e = 0.0f;
    #pragma unroll
    for (int c4 = 0; c4 < 16; ++c4) {
      float4 q4 = *(const float4*)&Qs[hl][4*c4];
      e += q4.x*kreg[4*c4+0] + q4.y*kreg[4*c4+1]
         + q4.z*kreg[4*c4+2] + q4.w*kreg[4*c4+3];
    }
    e = (gok && h < L) ? e : 0.0f;
    if (g == h) e = -INFINITY;
    ab[(size_t)h * WW * 64] = e;
  }
}

// ---------------------------------------------------------------------------
// energyW + softmax over [eH | eW]; writes bf16 probs to attHb / attWb.
// grid (H, B, 2): z selects 32 w-rows; 4 waves x 8 rows each.
// ---------------------------------------------------------------------------
__global__ __launch_bounds__(256) void energyW_softmax_kernel(
    const float* __restrict__ qt, const float* __restrict__ kt,
    const float* __restrict__ eH,
    __bf16* __restrict__ attHb, __bf16* __restrict__ attWb,
    const int* __restrict__ len_p)
{
  const int tid = threadIdx.x;
  const int h = blockIdx.x, b = blockIdx.y, zz = blockIdx.z;
  int L = *len_p; L = L < 0 ? 0 : (L > 64 ? 64 : L);
  __shared__ float Qs[32][68];
  __shared__ float Ks[64][68];
  {
    const int c = tid & 63, grp = tid >> 6;
    const float* qb = qt + ((size_t)b * PP + (size_t)h * WW) * CQ + c;
    const float* kb = kt + ((size_t)b * PP + (size_t)h * WW) * CQ + c;
    #pragma unroll
    for (int r = 0; r < 8; ++r) {
      int wl = grp*8 + r;
      Qs[wl][c] = qb[(size_t)(zz*32 + wl) * CQ];
    }
    #pragma unroll
    for (int r = 0; r < 16; ++r) {
      int wk = grp*16 + r;
      Ks[wk][c] = kb[(size_t)wk * CQ];
    }
  }
  __syncthreads();
  const int g  = tid & 63;
  const int wg = tid >> 6;
  float kreg[64];
  #pragma unroll
  for (int c = 0; c < 64; ++c) kreg[c] = (c < L) ? Ks[g][c] : 0.0f;
  const bool gok = (g < L);
  const float* ehb = eH + (((size_t)b * HH + h) * WW) * 64 + g;
  __bf16* ahb = attHb + (((size_t)b * HH + h) * WW) * 64 + g;
  __bf16* awb = attWb + (((size_t)b * HH + h) * WW) * 64 + g;
  for (int r = 0; r < 8; ++r) {
    int wl = wg*8 + r;
    int w  = zz*32 + wl;
    float e = 0.0f;
    #pragma unroll
    for (int c4 = 0; c4 < 16; ++c4) {
      float4 q4 = *(const float4*)&Qs[wl][4*c4];
      e += q4.x*kreg[4*c4+0] + q4.y*kreg[4*c4+1]
         + q4.z*kreg[4*c4+2] + q4.w*kreg[4*c4+3];
    }
    e = (gok && w < L) ? e : 0.0f;
    float eh = ehb[(size_t)w * 64];
    float m = fmaxf(e, eh);
    #pragma unroll
    for (int d = 32; d > 0; d >>= 1) m = fmaxf(m, __shfl_xor(m, d, 64));
    float pe = __expf(e  - m);
    float ph = __expf(eh - m);
    float s = pe + ph;
    #pragma unroll
    for (int d = 32; d > 0; d >>= 1) s += __shfl_xor(s, d, 64);
    float inv = 1.0f / s;
    ahb[(size_t)w * 64] = (__bf16)(ph * inv);
    awb[(size_t)w * 64] = (__bf16)(pe * inv);
  }
}

// ---------------------------------------------------------------------------
// V staging into 16x16-subtiled LDS (64j x 64c tile) with j-permutation so
// ds_read_b64_tr_b16 (lane addr = subtile_base + 8*l) yields B-fragments:
//   s=j>>5, p=(j>>2)&1, t=((j&31)>>3)*4+(j&3), cb=c>>4
//   entry offset = ((s*2+p)*4 + cb)*256 + t*16 + (c&15)   [bf16 entries]
// ---------------------------------------------------------------------------
__device__ __forceinline__ int vsub64_off(int j, int c) {
  int s  = j >> 5;
  int p  = (j >> 2) & 1;
  int t  = ((j & 31) >> 3) * 4 + (j & 3);
  return ((s*2 + p)*4 + (c >> 4))*256 + t*16 + (c & 15);
}

// ---------------------------------------------------------------------------
// outH (MFMA): per (b,w,cq): oH[b,h,w, cq*64+c'] = sum_j attH[h,j]*v[j*64+w,c]
// grid (W, 8, B), block 256 (4 waves; wave wv owns h rows wv*16..+15).
// ---------------------------------------------------------------------------
__global__ __launch_bounds__(256) void outH_mfma_kernel(
    const __bf16* __restrict__ attHb, const __bf16* __restrict__ vt,
    __bf16* __restrict__ oH)
{
  const int tid = threadIdx.x;
  const int w = blockIdx.x, cq = blockIdx.y, b = blockIdx.z;
  const int l = tid & 63, wv = tid >> 6;
  const int lm = l & 15, lk = l >> 4;

  __shared__ __align__(16) __bf16 Bs[4096];

  #pragma unroll
  for (int i = 0; i < 2; ++i) {
    int j  = i*32 + (tid >> 3);
    int c0 = (tid & 7) * 8;
    bf16x8 v8 = *(const bf16x8*)(vt + ((size_t)b*PP + (size_t)j*WW + w)*CH + cq*64 + c0);
    *(bf16x8*)&Bs[vsub64_off(j, c0)] = v8;
  }

  const int hrow = wv*16 + lm;
  const __bf16* ab = attHb + (((size_t)b*HH + hrow)*WW + w)*64;
  bf16x8 af[2];
  af[0] = *(const bf16x8*)(ab + lk*8);
  af[1] = *(const bf16x8*)(ab + 32 + lk*8);
  __syncthreads();

  const unsigned bs_base = lds_off(&Bs[0]);
  f32x4 acc[4];
  #pragma unroll
  for (int f = 0; f < 4; ++f) acc[f] = (f32x4){0.f,0.f,0.f,0.f};
  #pragma unroll
  for (int s = 0; s < 2; ++s) {
    bf16x8 bfr[4];
    #pragma unroll
    for (int f = 0; f < 4; ++f) {
      unsigned base = bs_base + (unsigned)((((s*2)*4 + f)*512)) + (unsigned)(l*8);
      bf16x4 t0 = ds_tr16(base);
      bf16x4 t1 = ds_tr16(base + 2048);   // p=1 block
      bfr[f] = __builtin_shufflevector(t0, t1, 0,1,2,3,4,5,6,7);
    }
    asm volatile("s_waitcnt lgkmcnt(0)");
    __builtin_amdgcn_sched_barrier(0);
    #pragma unroll
    for (int f = 0; f < 4; ++f)
      acc[f] = __builtin_amdgcn_mfma_f32_16x16x32_bf16(af[s], bfr[f], acc[f], 0,0,0);
  }
  __bf16* ob = oH + (((size_t)b * HH) * WW + w) * CH + cq*64;
  #pragma unroll
  for (int f = 0; f < 4; ++f) {
    #pragma unroll
    for (int r = 0; r < 4; ++r) {
      int h = wv*16 + lk*4 + r;
      ob[(size_t)h * WW * CH + f*16 + lm] = (__bf16)acc[f][r];
    }
  }
}

// ---------------------------------------------------------------------------
// outW (MFMA) + final: per (b,h,cq): out = gamma*(outW + oH) + x1
// grid (H, 8, B), block 256. oH + x1 prefetched into registers at start;
// LDS union: Bs (8KB) then Sc [64][69] f32 (17.7KB).
// ---------------------------------------------------------------------------
__global__ __launch_bounds__(256) void outW_final_kernel(
    const __bf16* __restrict__ attWb, const __bf16* __restrict__ vt,
    const __bf16* __restrict__ oH,
    const float* __restrict__ x1, const float* __restrict__ gamma_p,
    float* __restrict__ out)
{
  const int tid = threadIdx.x;
  const int h = blockIdx.x, cq = blockIdx.y, b = blockIdx.z;
  const int l = tid & 63, wv = tid >> 6;
  const int lm = l & 15, lk = l >> 4;
  const float gamma = *gamma_p;

  __shared__ __align__(16) char smem[64*69*4];   // 17664 B
  __bf16* Bs = (__bf16*)smem;                    // 4096 entries (8 KB)
  typedef float ScRow[69];
  ScRow* Sc = (ScRow*)smem;                      // [64][69] f32

  #pragma unroll
  for (int i = 0; i < 2; ++i) {
    int j  = i*32 + (tid >> 3);
    int c0 = (tid & 7) * 8;
    bf16x8 v8 = *(const bf16x8*)(vt + ((size_t)b*PP + (size_t)h*WW + j)*CH + cq*64 + c0);
    *(bf16x8*)&Bs[vsub64_off(j, c0)] = v8;
  }

  const int wrow = wv*16 + lm;
  const __bf16* ab = attWb + (((size_t)b*HH + h)*WW + wrow)*64;
  bf16x8 af[2];
  af[0] = *(const bf16x8*)(ab + lk*8);
  af[1] = *(const bf16x8*)(ab + 32 + lk*8);

  // final-pass layout prefetch (T14): lane -> (w = wl, c rows ci = cg*16+r2)
  const int wl = tid & 63, cg = tid >> 6;
  const __bf16* ohb = oH + ((((size_t)b*HH + h) * WW) + wl) * CH + cq*64 + cg*16;
  bf16x8 ohr[2];
  ohr[0] = *(const bf16x8*)(ohb);
  ohr[1] = *(const bf16x8*)(ohb + 8);
  float x1r[16];
  {
    const float* x1b = x1 + ((size_t)b*CH + cq*64 + cg*16)*PP + (size_t)h*WW + wl;
    #pragma unroll
    for (int r2 = 0; r2 < 16; ++r2)
      x1r[r2] = x1b[(size_t)r2 * PP];
  }
  __syncthreads();

  const unsigned bs_base = lds_off(&Bs[0]);
  f32x4 acc[4];
  #pragma unroll
  for (int f = 0; f < 4; ++f) acc[f] = (f32x4){0.f,0.f,0.f,0.f};
  #pragma unroll
  for (int s = 0; s < 2; ++s) {
    bf16x8 bfr[4];
    #pragma unroll
    for (int f = 0; f < 4; ++f) {
      unsigned base = bs_base + (unsigned)((((s*2)*4 + f)*512)) + (unsigned)(l*8);
      bf16x4 t0 = ds_tr16(base);
      bf16x4 t1 = ds_tr16(base + 2048);
      bfr[f] = __builtin_shufflevector(t0, t1, 0,1,2,3,4,5,6,7);
    }
    asm volatile("s_waitcnt lgkmcnt(0)");
    __builtin_amdgcn_sched_barrier(0);
    #pragma unroll
    for (int f = 0; f < 4; ++f)
      acc[f] = __builtin_amdgcn_mfma_f32_16x16x32_bf16(af[s], bfr[f], acc[f], 0,0,0);
  }

  __syncthreads();   // all tr16 reads of Bs done (Sc aliases Bs)
  #pragma unroll
  for (int f = 0; f < 4; ++f) {
    #pragma unroll
    for (int r = 0; r < 4; ++r)
      Sc[wv*16 + lk*4 + r][f*16 + lm] = acc[f][r];
  }
  __syncthreads();
  {
    float* obp = out + ((size_t)b*CH + cq*64 + cg*16)*PP + (size_t)h*WW + wl;
    #pragma unroll
    for (int r2 = 0; r2 < 16; ++r2) {
      float oh = (float)ohr[r2 >> 3][r2 & 7];
      obp[(size_t)r2 * PP] = gamma * (Sc[wl][cg*16 + r2] + oh) + x1r[r2];
    }
  }
}

// ---------------------------------------------------------------------------
extern "C" void kernel_launch(void* const* d_in, const int* in_sizes, int n_in,
                              void* d_out, int out_size, void* d_ws, size_t ws_size,
                              hipStream_t stream)
{
  const float* x1 = (const float*)d_in[0];
  const float* x2 = (const float*)d_in[1];
  const float* x3 = (const float*)d_in[2];
  const float* Wq = (const float*)d_in[3];
  const float* bq = (const float*)d_in[4];
  const float* Wk = (const float*)d_in[5];
  const float* bk = (const float*)d_in[6];
  const float* Wv = (const float*)d_in[7];
  const float* bv = (const float*)d_in[8];
  const float* gamma = (const float*)d_in[9];
  const int*   len   = (const int*)d_in[10];
  float* out = (float*)d_out;

  // workspace layout (96 MiB total):
  float*  q_t   = (float*)d_ws;                           // (B,P,64)   f32   8 MiB
  float*  k_t   = q_t + (size_t)BB * PP * CQ;             // (B,P,64)   f32   8 MiB
  float*  eH    = k_t + (size_t)BB * PP * CQ;             // (B,H,W,64) f32   8 MiB
  __bf16* attHb = (__bf16*)(eH + (size_t)BB * PP * 64);   // (B,H,W,64) bf16  4 MiB
  __bf16* attWb = attHb + (size_t)BB * PP * 64;           // (B,H,W,64) bf16  4 MiB
  __bf16* v_t   = attWb + (size_t)BB * PP * 64;           // (B,P,512)  bf16 32 MiB
  __bf16* oH    = v_t + (size_t)BB * PP * CH;             // (B,H,W,512)bf16 32 MiB

  dim3 blk(256);
  // all projections in ONE launch; grid (mblk, role) so all 6 roles of an
  // m-block share one XCD's L2 (id%8 == mblk%8).
  proj_all_kernel<<<dim3(BB*PP/128, 6), blk, 0, stream>>>(
      x3, Wv, bv, v_t,  x1, Wq, bq, q_t,  x2, Wk, bk, k_t);

  energyH_kernel<<<dim3(WW, BB, 2), blk, 0, stream>>>(q_t, k_t, eH, len);
  energyW_softmax_kernel<<<dim3(HH, BB, 2), blk, 0, stream>>>(q_t, k_t, eH, attHb, attWb, len);
  outH_mfma_kernel<<<dim3(WW, 8, BB), blk, 0, stream>>>(attHb, v_t, oH);
  outW_final_kernel<<<dim3(HH, 8, BB), blk, 0, stream>>>(attWb, v_t, oH, x1, gamma, out);
}

// Round 14
// 144.178 us; speedup vs baseline: 1.1775x; 1.0004x over previous
//
#include <hip/hip_runtime.h>
#include <math.h>
#include <type_traits>

#define CH 512
#define CQ 64
#define HH 64
#define WW 64
#define PP (HH*WW)   // 4096
#define BB 8

typedef __bf16 bf16x8 __attribute__((ext_vector_type(8)));
typedef __bf16 bf16x4 __attribute__((ext_vector_type(4)));
typedef float  f32x4  __attribute__((ext_vector_type(4)));

// ---- LDS helpers (inline asm; keep asm ds ops and compiler ds ops in
// ---- disjoint regions, one lgkmcnt(0)+sched_barrier(0) before MFMAs) ----
__device__ __forceinline__ unsigned lds_off(const void* p) {
  return (unsigned)(size_t)(__attribute__((address_space(3))) const void*)p;
}
__device__ __forceinline__ bf16x4 ds_tr16(unsigned addr) {
  bf16x4 r;
  asm volatile("ds_read_b64_tr_b16 %0, %1" : "=v"(r) : "v"(addr));
  return r;
}

// ---------------------------------------------------------------------------
// proj_body (R11-proven inner loop): one 128xBN tile of
// Y[m,o] = sum_c X[b,c,p]*W[o,c] + bias[o].
// 256 thr, 2x2 waves, wave tile 64x(FN*16); dbuf LDS; static depth-2 A
// prefetch (named ra0/ra1, phase-unrolled; rule-#20 safe). Plain bf16.
// A loads: dword per (m,k) elem, conflict-free bf16x8 row writes.
// ---------------------------------------------------------------------------
template<int FM, int FN, int NOUT, typename OutT>
__device__ __forceinline__ void proj_body(
    __bf16* AsBase, __bf16* BsBase,
    const float* __restrict__ X, const float* __restrict__ W,
    const float* __restrict__ bias, OutT* __restrict__ Y,
    int mblk, int nblk)
{
  constexpr int BM = 32 * FM;
  constexpr int BN = 32 * FN;
  constexpr int GA = BM / 64;
  constexpr int GB = BN / 64;
  typedef __bf16 (*TileA)[BM][40];
  typedef __bf16 (*TileB)[BN][40];
  TileA As = (TileA)AsBase;   // [2][BM][40]
  TileB Bs = (TileB)BsBase;   // [2][BN][40]

  const int tid = threadIdx.x;
  const int b     = mblk >> 12;             // BM divides 4096
  const int pbase = mblk & 4095;
  const float* Xb = X + (size_t)b * CH * PP;

  const int l  = tid & 63;
  const int wv = tid >> 6;
  const int wr = wv >> 1, wc = wv & 1;
  const int lm = l & 15, lk = l >> 4;

  int ma[GA], ka[GA];
  #pragma unroll
  for (int gi = 0; gi < GA; ++gi) {
    int g = tid + gi * 256;
    ma[gi] = g % BM;
    ka[gi] = (g / BM) * 8;
  }
  int nb_[GB], kb_[GB];
  #pragma unroll
  for (int gi = 0; gi < GB; ++gi) {
    int g = tid + gi * 256;
    nb_[gi] = g >> 2;
    kb_[gi] = (g & 3) * 8;
  }

  float ra0[GA][8], ra1[GA][8];   // depth-2 A prefetch (named, static idx)
  float rb[GB][8];                // depth-1 B prefetch

  auto loadA = [&](float (&ra)[GA][8], int c0) {
    #pragma unroll
    for (int gi = 0; gi < GA; ++gi)
      #pragma unroll
      for (int jj = 0; jj < 8; ++jj)
        ra[gi][jj] = Xb[(size_t)(c0 + ka[gi] + jj) * PP + pbase + ma[gi]];
  };
  auto loadB = [&](int c0) {
    #pragma unroll
    for (int gi = 0; gi < GB; ++gi) {
      const float* src = W + (size_t)(nblk + nb_[gi]) * CH + c0 + kb_[gi];
      float4 f0 = *(const float4*)src;
      float4 f1 = *(const float4*)(src + 4);
      rb[gi][0]=f0.x; rb[gi][1]=f0.y; rb[gi][2]=f0.z; rb[gi][3]=f0.w;
      rb[gi][4]=f1.x; rb[gi][5]=f1.y; rb[gi][6]=f1.z; rb[gi][7]=f1.w;
    }
  };

  f32x4 acc[FM][FN];
  #pragma unroll
  for (int j = 0; j < FN; ++j) {
    float bvj = bias[nblk + wc*FN*16 + j*16 + lm];
    #pragma unroll
    for (int i = 0; i < FM; ++i) {
      acc[i][j][0] = bvj; acc[i][j][1] = bvj;
      acc[i][j][2] = bvj; acc[i][j][3] = bvj;
    }
  }

  auto phase = [&](int t, auto par_c, float (&ra)[GA][8]) {
    constexpr int PAR = decltype(par_c)::value;
    #pragma unroll
    for (int gi = 0; gi < GA; ++gi) {
      bf16x8 hv;
      #pragma unroll
      for (int jj = 0; jj < 8; ++jj) hv[jj] = (__bf16)ra[gi][jj];
      *(bf16x8*)&As[PAR][ma[gi]][ka[gi]] = hv;
    }
    #pragma unroll
    for (int gi = 0; gi < GB; ++gi) {
      bf16x8 hv;
      #pragma unroll
      for (int jj = 0; jj < 8; ++jj) hv[jj] = (__bf16)rb[gi][jj];
      *(bf16x8*)&Bs[PAR][nb_[gi]][kb_[gi]] = hv;
    }
    __syncthreads();
    if (t < 15) loadB((t+1)*32);
    if (t < 14) loadA(ra, (t+2)*32);
    bf16x8 af[FM], bfr[FN];
    #pragma unroll
    for (int i = 0; i < FM; ++i)
      af[i] = *(const bf16x8*)&As[PAR][wr*FM*16 + i*16 + lm][lk*8];
    #pragma unroll
    for (int j = 0; j < FN; ++j)
      bfr[j] = *(const bf16x8*)&Bs[PAR][wc*FN*16 + j*16 + lm][lk*8];
    #pragma unroll
    for (int i = 0; i < FM; ++i)
      #pragma unroll
      for (int j = 0; j < FN; ++j)
        acc[i][j] = __builtin_amdgcn_mfma_f32_16x16x32_bf16(
            af[i], bfr[j], acc[i][j], 0, 0, 0);
  };

  loadA(ra0, 0); loadB(0); loadA(ra1, 32);
  for (int tt = 0; tt < 8; ++tt) {
    phase(2*tt,     std::integral_constant<int,0>{}, ra0);
    phase(2*tt + 1, std::integral_constant<int,1>{}, ra1);
  }

  // epilogue: C/D layout col=lane&15, row=(lane>>4)*4+r
  #pragma unroll
  for (int i = 0; i < FM; ++i) {
    #pragma unroll
    for (int j = 0; j < FN; ++j) {
      #pragma unroll
      for (int r = 0; r < 4; ++r) {
        int mg = mblk + wr*FM*16 + i*16 + lk*4 + r;
        int ng = nblk + wc*FN*16 + j*16 + lm;
        Y[(size_t)mg * NOUT + ng] = (OutT)acc[i][j][r];
      }
    }
  }
}

// ---------------------------------------------------------------------------
// proj_all: one launch for v,q,k so blocks co-reside (latency hiding).
// grid (256, 6): x = m-block, y = role (0..3: v n-col; 4: q; 5: k).
// linear id = x + 256*y -> id%8 = mblk%8, so all 6 roles of an m-block land
// on the SAME XCD (shared x-panel reads become L2 hits; R12: FETCH -30%).
// ---------------------------------------------------------------------------
__global__ __launch_bounds__(256) void proj_all_kernel(
    const float* __restrict__ x3, const float* __restrict__ Wv,
    const float* __restrict__ bv, __bf16* __restrict__ v_t,
    const float* __restrict__ x1, const float* __restrict__ Wq,
    const float* __restrict__ bq, float* __restrict__ q_t,
    const float* __restrict__ x2, const float* __restrict__ Wk,
    const float* __restrict__ bk, float* __restrict__ k_t)
{
  __shared__ __align__(16) __bf16 AsPool[2*128*40];   // 20480 B
  __shared__ __align__(16) __bf16 BsPool[2*128*40];   // 20480 B
  const int role = blockIdx.y;
  const int mblk = blockIdx.x * 128;
  if (role < 4) {
    proj_body<4,4, CH, __bf16>(AsPool, BsPool, x3, Wv, bv, v_t, mblk, role*128);
  } else if (role == 4) {
    proj_body<4,2, CQ, float >(AsPool, BsPool, x1, Wq, bq, q_t, mblk, 0);
  } else {
    proj_body<4,2, CQ, float >(AsPool, BsPool, x2, Wk, bk, k_t, mblk, 0);
  }
}

// ---------------------------------------------------------------------------
// energyH: eH[b,h,w,g] = (h<L && g<L) ? q.k : 0, -inf diag.
// grid (W, B, 2): z selects 32 h-rows; 4 waves x 8 rows each.
// ---------------------------------------------------------------------------
__global__ __launch_bounds__(256) void energyH_kernel(
    const float* __restrict__ qt, const float* __restrict__ kt,
    float* __restrict__ eH, const int* __restrict__ len_p)
{
  const int tid = threadIdx.x;
  const int w = blockIdx.x, b = blockIdx.y, zz = blockIdx.z;
  int L = *len_p; L = L < 0 ? 0 : (L > 64 ? 64 : L);
  __shared__ float Qs[32][68];
  __shared__ float Ks[64][68];
  {
    const int c = tid & 63, grp = tid >> 6;
    const float* qb = qt + ((size_t)b * PP + w) * CQ + c;
    const float* kb = kt + ((size_t)b * PP + w) * CQ + c;
    #pragma unroll
    for (int r = 0; r < 8; ++r) {
      int hl = grp*8 + r;
      Qs[hl][c] = qb[(size_t)(zz*32 + hl) * WW * CQ];
    }
    #pragma unroll
    for (int r = 0; r < 16; ++r) {
      int hk = grp*16 + r;
      Ks[hk][c] = kb[(size_t)hk * WW * CQ];
    }
  }
  __syncthreads();
  const int g  = tid & 63;
  const int wg = tid >> 6;
  float kreg[64];
  #pragma unroll
  for (int c = 0; c < 64; ++c) kreg[c] = (c < L) ? Ks[g][c] : 0.0f;
  const bool gok = (g < L);
  float* ab = eH + (((size_t)b * HH) * WW + w) * 64 + g;
  for (int r = 0; r < 8; ++r) {
    int hl = wg*8 + r;
    int h  = zz*32 + hl;
    float e = 0.0f;
    #pragma unroll
    for (int c4 = 0; c4 < 16; ++c4) {
      float4 q4 = *(const float4*)&Qs[hl][4*c4];
      e += q4.x*kreg[4*c4+0] + q4.y*kreg[4*c4+1]
         + q4.z*kreg[4*c4+2] + q4.w*kreg[4*c4+3];
    }
    e = (gok && h < L) ? e : 0.0f;
    if (g == h) e = -INFINITY;
    ab[(size_t)h * WW * 64] = e;
  }
}

// ---------------------------------------------------------------------------
// energyW + softmax over [eH | eW]; writes bf16 probs to attHb / attWb.
// grid (H, B, 2): z selects 32 w-rows; 4 waves x 8 rows each.
// ---------------------------------------------------------------------------
__global__ __launch_bounds__(256) void energyW_softmax_kernel(
    const float* __restrict__ qt, const float* __restrict__ kt,
    const float* __restrict__ eH,
    __bf16* __restrict__ attHb, __bf16* __restrict__ attWb,
    const int* __restrict__ len_p)
{
  const int tid = threadIdx.x;
  const int h = blockIdx.x, b = blockIdx.y, zz = blockIdx.z;
  int L = *len_p; L = L < 0 ? 0 : (L > 64 ? 64 : L);
  __shared__ float Qs[32][68];
  __shared__ float Ks[64][68];
  {
    const int c = tid & 63, grp = tid >> 6;
    const float* qb = qt + ((size_t)b * PP + (size_t)h * WW) * CQ + c;
    const float* kb = kt + ((size_t)b * PP + (size_t)h * WW) * CQ + c;
    #pragma unroll
    for (int r = 0; r < 8; ++r) {
      int wl = grp*8 + r;
      Qs[wl][c] = qb[(size_t)(zz*32 + wl) * CQ];
    }
    #pragma unroll
    for (int r = 0; r < 16; ++r) {
      int wk = grp*16 + r;
      Ks[wk][c] = kb[(size_t)wk * CQ];
    }
  }
  __syncthreads();
  const int g  = tid & 63;
  const int wg = tid >> 6;
  float kreg[64];
  #pragma unroll
  for (int c = 0; c < 64; ++c) kreg[c] = (c < L) ? Ks[g][c] : 0.0f;
  const bool gok = (g < L);
  const float* ehb = eH + (((size_t)b * HH + h) * WW) * 64 + g;
  __bf16* ahb = attHb + (((size_t)b * HH + h) * WW) * 64 + g;
  __bf16* awb = attWb + (((size_t)b * HH + h) * WW) * 64 + g;
  for (int r = 0; r < 8; ++r) {
    int wl = wg*8 + r;
    int w  = zz*32 + wl;
    float e = 0.0f;
    #pragma unroll
    for (int c4 = 0; c4 < 16; ++c4) {
      float4 q4 = *(const float4*)&Qs[wl][4*c4];
      e += q4.x*kreg[4*c4+0] + q4.y*kreg[4*c4+1]
         + q4.z*kreg[4*c4+2] + q4.w*kreg[4*c4+3];
    }
    e = (gok && w < L) ? e : 0.0f;
    float eh = ehb[(size_t)w * 64];
    float m = fmaxf(e, eh);
    #pragma unroll
    for (int d = 32; d > 0; d >>= 1) m = fmaxf(m, __shfl_xor(m, d, 64));
    float pe = __expf(e  - m);
    float ph = __expf(eh - m);
    float s = pe + ph;
    #pragma unroll
    for (int d = 32; d > 0; d >>= 1) s += __shfl_xor(s, d, 64);
    float inv = 1.0f / s;
    ahb[(size_t)w * 64] = (__bf16)(ph * inv);
    awb[(size_t)w * 64] = (__bf16)(pe * inv);
  }
}

// ---------------------------------------------------------------------------
// V staging into 16x16-subtiled LDS (64j x 64c tile) with j-permutation so
// ds_read_b64_tr_b16 (lane addr = subtile_base + 8*l) yields B-fragments:
//   s=j>>5, p=(j>>2)&1, t=((j&31)>>3)*4+(j&3), cb=c>>4
//   entry offset = ((s*2+p)*4 + cb)*256 + t*16 + (c&15)   [bf16 entries]
// ---------------------------------------------------------------------------
__device__ __forceinline__ int vsub64_off(int j, int c) {
  int s  = j >> 5;
  int p  = (j >> 2) & 1;
  int t  = ((j & 31) >> 3) * 4 + (j & 3);
  return ((s*2 + p)*4 + (c >> 4))*256 + t*16 + (c & 15);
}

// ---------------------------------------------------------------------------
// outH (MFMA): per (b,w,cq): oH[b,h,w, cq*64+c'] = sum_j attH[h,j]*v[j*64+w,c]
// grid (W, 8, B), block 256 (4 waves; wave wv owns h rows wv*16..+15).
// ---------------------------------------------------------------------------
__global__ __launch_bounds__(256) void outH_mfma_kernel(
    const __bf16* __restrict__ attHb, const __bf16* __restrict__ vt,
    __bf16* __restrict__ oH)
{
  const int tid = threadIdx.x;
  const int w = blockIdx.x, cq = blockIdx.y, b = blockIdx.z;
  const int l = tid & 63, wv = tid >> 6;
  const int lm = l & 15, lk = l >> 4;

  __shared__ __align__(16) __bf16 Bs[4096];

  #pragma unroll
  for (int i = 0; i < 2; ++i) {
    int j  = i*32 + (tid >> 3);
    int c0 = (tid & 7) * 8;
    bf16x8 v8 = *(const bf16x8*)(vt + ((size_t)b*PP + (size_t)j*WW + w)*CH + cq*64 + c0);
    *(bf16x8*)&Bs[vsub64_off(j, c0)] = v8;
  }

  const int hrow = wv*16 + lm;
  const __bf16* ab = attHb + (((size_t)b*HH + hrow)*WW + w)*64;
  bf16x8 af[2];
  af[0] = *(const bf16x8*)(ab + lk*8);
  af[1] = *(const bf16x8*)(ab + 32 + lk*8);
  __syncthreads();

  const unsigned bs_base = lds_off(&Bs[0]);
  f32x4 acc[4];
  #pragma unroll
  for (int f = 0; f < 4; ++f) acc[f] = (f32x4){0.f,0.f,0.f,0.f};
  #pragma unroll
  for (int s = 0; s < 2; ++s) {
    bf16x8 bfr[4];
    #pragma unroll
    for (int f = 0; f < 4; ++f) {
      unsigned base = bs_base + (unsigned)((((s*2)*4 + f)*512)) + (unsigned)(l*8);
      bf16x4 t0 = ds_tr16(base);
      bf16x4 t1 = ds_tr16(base + 2048);   // p=1 block
      bfr[f] = __builtin_shufflevector(t0, t1, 0,1,2,3,4,5,6,7);
    }
    asm volatile("s_waitcnt lgkmcnt(0)");
    __builtin_amdgcn_sched_barrier(0);
    #pragma unroll
    for (int f = 0; f < 4; ++f)
      acc[f] = __builtin_amdgcn_mfma_f32_16x16x32_bf16(af[s], bfr[f], acc[f], 0,0,0);
  }
  __bf16* ob = oH + (((size_t)b * HH) * WW + w) * CH + cq*64;
  #pragma unroll
  for (int f = 0; f < 4; ++f) {
    #pragma unroll
    for (int r = 0; r < 4; ++r) {
      int h = wv*16 + lk*4 + r;
      ob[(size_t)h * WW * CH + f*16 + lm] = (__bf16)acc[f][r];
    }
  }
}

// ---------------------------------------------------------------------------
// outW (MFMA) + final: per (b,h,cq): out = gamma*(outW + oH) + x1
// grid (H, 8, B), block 256. oH + x1 prefetched into registers at start;
// LDS union: Bs (8KB) then Sc [64][69] f32 (17.7KB).
// ---------------------------------------------------------------------------
__global__ __launch_bounds__(256) void outW_final_kernel(
    const __bf16* __restrict__ attWb, const __bf16* __restrict__ vt,
    const __bf16* __restrict__ oH,
    const float* __restrict__ x1, const float* __restrict__ gamma_p,
    float* __restrict__ out)
{
  const int tid = threadIdx.x;
  const int h = blockIdx.x, cq = blockIdx.y, b = blockIdx.z;
  const int l = tid & 63, wv = tid >> 6;
  const int lm = l & 15, lk = l >> 4;
  const float gamma = *gamma_p;

  __shared__ __align__(16) char smem[64*69*4];   // 17664 B
  __bf16* Bs = (__bf16*)smem;                    // 4096 entries (8 KB)
  typedef float ScRow[69];
  ScRow* Sc = (ScRow*)smem;                      // [64][69] f32

  #pragma unroll
  for (int i = 0; i < 2; ++i) {
    int j  = i*32 + (tid >> 3);
    int c0 = (tid & 7) * 8;
    bf16x8 v8 = *(const bf16x8*)(vt + ((size_t)b*PP + (size_t)h*WW + j)*CH + cq*64 + c0);
    *(bf16x8*)&Bs[vsub64_off(j, c0)] = v8;
  }

  const int wrow = wv*16 + lm;
  const __bf16* ab = attWb + (((size_t)b*HH + h)*WW + wrow)*64;
  bf16x8 af[2];
  af[0] = *(const bf16x8*)(ab + lk*8);
  af[1] = *(const bf16x8*)(ab + 32 + lk*8);

  // final-pass layout prefetch (T14): lane -> (w = wl, c rows ci = cg*16+r2)
  const int wl = tid & 63, cg = tid >> 6;
  const __bf16* ohb = oH + ((((size_t)b*HH + h) * WW) + wl) * CH + cq*64 + cg*16;
  bf16x8 ohr[2];
  ohr[0] = *(const bf16x8*)(ohb);
  ohr[1] = *(const bf16x8*)(ohb + 8);
  float x1r[16];
  {
    const float* x1b = x1 + ((size_t)b*CH + cq*64 + cg*16)*PP + (size_t)h*WW + wl;
    #pragma unroll
    for (int r2 = 0; r2 < 16; ++r2)
      x1r[r2] = x1b[(size_t)r2 * PP];
  }
  __syncthreads();

  const unsigned bs_base = lds_off(&Bs[0]);
  f32x4 acc[4];
  #pragma unroll
  for (int f = 0; f < 4; ++f) acc[f] = (f32x4){0.f,0.f,0.f,0.f};
  #pragma unroll
  for (int s = 0; s < 2; ++s) {
    bf16x8 bfr[4];
    #pragma unroll
    for (int f = 0; f < 4; ++f) {
      unsigned base = bs_base + (unsigned)((((s*2)*4 + f)*512)) + (unsigned)(l*8);
      bf16x4 t0 = ds_tr16(base);
      bf16x4 t1 = ds_tr16(base + 2048);
      bfr[f] = __builtin_shufflevector(t0, t1, 0,1,2,3,4,5,6,7);
    }
    asm volatile("s_waitcnt lgkmcnt(0)");
    __builtin_amdgcn_sched_barrier(0);
    #pragma unroll
    for (int f = 0; f < 4; ++f)
      acc[f] = __builtin_amdgcn_mfma_f32_16x16x32_bf16(af[s], bfr[f], acc[f], 0,0,0);
  }

  __syncthreads();   // all tr16 reads of Bs done (Sc aliases Bs)
  #pragma unroll
  for (int f = 0; f < 4; ++f) {
    #pragma unroll
    for (int r = 0; r < 4; ++r)
      Sc[wv*16 + lk*4 + r][f*16 + lm] = acc[f][r];
  }
  __syncthreads();
  {
    float* obp = out + ((size_t)b*CH + cq*64 + cg*16)*PP + (size_t)h*WW + wl;
    #pragma unroll
    for (int r2 = 0; r2 < 16; ++r2) {
      float oh = (float)ohr[r2 >> 3][r2 & 7];
      obp[(size_t)r2 * PP] = gamma * (Sc[wl][cg*16 + r2] + oh) + x1r[r2];
    }
  }
}

// ---------------------------------------------------------------------------
extern "C" void kernel_launch(void* const* d_in, const int* in_sizes, int n_in,
                              void* d_out, int out_size, void* d_ws, size_t ws_size,
                              hipStream_t stream)
{
  const float* x1 = (const float*)d_in[0];
  const float* x2 = (const float*)d_in[1];
  const float* x3 = (const float*)d_in[2];
  const float* Wq = (const float*)d_in[3];
  const float* bq = (const float*)d_in[4];
  const float* Wk = (const float*)d_in[5];
  const float* bk = (const float*)d_in[6];
  const float* Wv = (const float*)d_in[7];
  const float* bv = (const float*)d_in[8];
  const float* gamma = (const float*)d_in[9];
  const int*   len   = (const int*)d_in[10];
  float* out = (float*)d_out;

  // workspace layout (96 MiB total):
  float*  q_t   = (float*)d_ws;                           // (B,P,64)   f32   8 MiB
  float*  k_t   = q_t + (size_t)BB * PP * CQ;             // (B,P,64)   f32   8 MiB
  float*  eH    = k_t + (size_t)BB * PP * CQ;             // (B,H,W,64) f32   8 MiB
  __bf16* attHb = (__bf16*)(eH + (size_t)BB * PP * 64);   // (B,H,W,64) bf16  4 MiB
  __bf16* attWb = attHb + (size_t)BB * PP * 64;           // (B,H,W,64) bf16  4 MiB
  __bf16* v_t   = attWb + (size_t)BB * PP * 64;           // (B,P,512)  bf16 32 MiB
  __bf16* oH    = v_t + (size_t)BB * PP * CH;             // (B,H,W,512)bf16 32 MiB

  dim3 blk(256);
  // all projections in ONE launch; grid (mblk, role) so all 6 roles of an
  // m-block share one XCD's L2 (id%8 == mblk%8; R12-validated, FETCH -30%).
  proj_all_kernel<<<dim3(BB*PP/128, 6), blk, 0, stream>>>(
      x3, Wv, bv, v_t,  x1, Wq, bq, q_t,  x2, Wk, bk, k_t);

  energyH_kernel<<<dim3(WW, BB, 2), blk, 0, stream>>>(q_t, k_t, eH, len);
  energyW_softmax_kernel<<<dim3(HH, BB, 2), blk, 0, stream>>>(q_t, k_t, eH, attHb, attWb, len);
  outH_mfma_kernel<<<dim3(WW, 8, BB), blk, 0, stream>>>(attHb, v_t, oH);
  outW_final_kernel<<<dim3(HH, 8, BB), blk, 0, stream>>>(attWb, v_t, oH, x1, gamma, out);
}

// Round 15
// 137.511 us; speedup vs baseline: 1.2345x; 1.0485x over previous
//
#include <hip/hip_runtime.h>
#include <math.h>
#include <type_traits>

#define CH 512
#define CQ 64
#define HH 64
#define WW 64
#define PP (HH*WW)   // 4096
#define BB 8

typedef __bf16 bf16x8 __attribute__((ext_vector_type(8)));
typedef __bf16 bf16x4 __attribute__((ext_vector_type(4)));
typedef float  f32x4  __attribute__((ext_vector_type(4)));

// ---- LDS helpers (inline asm; keep asm ds ops and compiler ds ops in
// ---- disjoint regions, one lgkmcnt(0)+sched_barrier(0) before MFMAs) ----
__device__ __forceinline__ unsigned lds_off(const void* p) {
  return (unsigned)(size_t)(__attribute__((address_space(3))) const void*)p;
}
__device__ __forceinline__ bf16x4 ds_tr16(unsigned addr) {
  bf16x4 r;
  asm volatile("ds_read_b64_tr_b16 %0, %1" : "=v"(r) : "v"(addr));
  return r;
}

// ---------------------------------------------------------------------------
// proj_body (R11-proven inner loop): one 128xBN tile of
// Y[m,o] = sum_c X[b,c,p]*W[o,c] + bias[o].
// 256 thr, 2x2 waves, wave tile 64x(FN*16); dbuf LDS; static depth-2 A
// prefetch (named ra0/ra1, phase-unrolled; rule-#20 safe). Plain bf16.
// ---------------------------------------------------------------------------
template<int FM, int FN, int NOUT, typename OutT>
__device__ __forceinline__ void proj_body(
    __bf16* AsBase, __bf16* BsBase,
    const float* __restrict__ X, const float* __restrict__ W,
    const float* __restrict__ bias, OutT* __restrict__ Y,
    int mblk, int nblk)
{
  constexpr int BM = 32 * FM;
  constexpr int BN = 32 * FN;
  constexpr int GA = BM / 64;
  constexpr int GB = BN / 64;
  typedef __bf16 (*TileA)[BM][40];
  typedef __bf16 (*TileB)[BN][40];
  TileA As = (TileA)AsBase;   // [2][BM][40]
  TileB Bs = (TileB)BsBase;   // [2][BN][40]

  const int tid = threadIdx.x;
  const int b     = mblk >> 12;             // BM divides 4096
  const int pbase = mblk & 4095;
  const float* Xb = X + (size_t)b * CH * PP;

  const int l  = tid & 63;
  const int wv = tid >> 6;
  const int wr = wv >> 1, wc = wv & 1;
  const int lm = l & 15, lk = l >> 4;

  int ma[GA], ka[GA];
  #pragma unroll
  for (int gi = 0; gi < GA; ++gi) {
    int g = tid + gi * 256;
    ma[gi] = g % BM;
    ka[gi] = (g / BM) * 8;
  }
  int nb_[GB], kb_[GB];
  #pragma unroll
  for (int gi = 0; gi < GB; ++gi) {
    int g = tid + gi * 256;
    nb_[gi] = g >> 2;
    kb_[gi] = (g & 3) * 8;
  }

  float ra0[GA][8], ra1[GA][8];   // depth-2 A prefetch (named, static idx)
  float rb[GB][8];                // depth-1 B prefetch

  auto loadA = [&](float (&ra)[GA][8], int c0) {
    #pragma unroll
    for (int gi = 0; gi < GA; ++gi)
      #pragma unroll
      for (int jj = 0; jj < 8; ++jj)
        ra[gi][jj] = Xb[(size_t)(c0 + ka[gi] + jj) * PP + pbase + ma[gi]];
  };
  auto loadB = [&](int c0) {
    #pragma unroll
    for (int gi = 0; gi < GB; ++gi) {
      const float* src = W + (size_t)(nblk + nb_[gi]) * CH + c0 + kb_[gi];
      float4 f0 = *(const float4*)src;
      float4 f1 = *(const float4*)(src + 4);
      rb[gi][0]=f0.x; rb[gi][1]=f0.y; rb[gi][2]=f0.z; rb[gi][3]=f0.w;
      rb[gi][4]=f1.x; rb[gi][5]=f1.y; rb[gi][6]=f1.z; rb[gi][7]=f1.w;
    }
  };

  f32x4 acc[FM][FN];
  #pragma unroll
  for (int j = 0; j < FN; ++j) {
    float bvj = bias[nblk + wc*FN*16 + j*16 + lm];
    #pragma unroll
    for (int i = 0; i < FM; ++i) {
      acc[i][j][0] = bvj; acc[i][j][1] = bvj;
      acc[i][j][2] = bvj; acc[i][j][3] = bvj;
    }
  }

  auto phase = [&](int t, auto par_c, float (&ra)[GA][8]) {
    constexpr int PAR = decltype(par_c)::value;
    #pragma unroll
    for (int gi = 0; gi < GA; ++gi) {
      bf16x8 hv;
      #pragma unroll
      for (int jj = 0; jj < 8; ++jj) hv[jj] = (__bf16)ra[gi][jj];
      *(bf16x8*)&As[PAR][ma[gi]][ka[gi]] = hv;
    }
    #pragma unroll
    for (int gi = 0; gi < GB; ++gi) {
      bf16x8 hv;
      #pragma unroll
      for (int jj = 0; jj < 8; ++jj) hv[jj] = (__bf16)rb[gi][jj];
      *(bf16x8*)&Bs[PAR][nb_[gi]][kb_[gi]] = hv;
    }
    __syncthreads();
    if (t < 15) loadB((t+1)*32);
    if (t < 14) loadA(ra, (t+2)*32);
    bf16x8 af[FM], bfr[FN];
    #pragma unroll
    for (int i = 0; i < FM; ++i)
      af[i] = *(const bf16x8*)&As[PAR][wr*FM*16 + i*16 + lm][lk*8];
    #pragma unroll
    for (int j = 0; j < FN; ++j)
      bfr[j] = *(const bf16x8*)&Bs[PAR][wc*FN*16 + j*16 + lm][lk*8];
    #pragma unroll
    for (int i = 0; i < FM; ++i)
      #pragma unroll
      for (int j = 0; j < FN; ++j)
        acc[i][j] = __builtin_amdgcn_mfma_f32_16x16x32_bf16(
            af[i], bfr[j], acc[i][j], 0, 0, 0);
  };

  loadA(ra0, 0); loadB(0); loadA(ra1, 32);
  for (int tt = 0; tt < 8; ++tt) {
    phase(2*tt,     std::integral_constant<int,0>{}, ra0);
    phase(2*tt + 1, std::integral_constant<int,1>{}, ra1);
  }

  // epilogue: C/D layout col=lane&15, row=(lane>>4)*4+r
  #pragma unroll
  for (int i = 0; i < FM; ++i) {
    #pragma unroll
    for (int j = 0; j < FN; ++j) {
      #pragma unroll
      for (int r = 0; r < 4; ++r) {
        int mg = mblk + wr*FM*16 + i*16 + lk*4 + r;
        int ng = nblk + wc*FN*16 + j*16 + lm;
        Y[(size_t)mg * NOUT + ng] = (OutT)acc[i][j][r];
      }
    }
  }
}

// ---------------------------------------------------------------------------
// proj_all: one launch for v,q,k. 1-D grid 1536, hybrid swizzle:
//   id = (m%8) + 8*(role + 6*(m/8))
// -> id%8 == m%8: all 6 roles of an m-block land on ONE XCD (L2 share,
//    R12-validated FETCH cut), AND within each 48-id window all 6 roles of
//    8 m-blocks interleave (R11-validated residency mix, no role tail).
// ---------------------------------------------------------------------------
__global__ __launch_bounds__(256) void proj_all_kernel(
    const float* __restrict__ x3, const float* __restrict__ Wv,
    const float* __restrict__ bv, __bf16* __restrict__ v_t,
    const float* __restrict__ x1, const float* __restrict__ Wq,
    const float* __restrict__ bq, float* __restrict__ q_t,
    const float* __restrict__ x2, const float* __restrict__ Wk,
    const float* __restrict__ bk, float* __restrict__ k_t)
{
  __shared__ __align__(16) __bf16 AsPool[2*128*40];   // 20480 B
  __shared__ __align__(16) __bf16 BsPool[2*128*40];   // 20480 B
  const int id   = blockIdx.x;
  const int low3 = id & 7;
  const int t    = id >> 3;
  const int role = t % 6;
  const int m    = (t / 6) * 8 + low3;    // 0..255
  const int mblk = m * 128;
  if (role < 4) {
    proj_body<4,4, CH, __bf16>(AsPool, BsPool, x3, Wv, bv, v_t, mblk, role*128);
  } else if (role == 4) {
    proj_body<4,2, CQ, float >(AsPool, BsPool, x1, Wq, bq, q_t, mblk, 0);
  } else {
    proj_body<4,2, CQ, float >(AsPool, BsPool, x2, Wk, bk, k_t, mblk, 0);
  }
}

// ---------------------------------------------------------------------------
// energyH: eH[b,h,w,g] = (h<L && g<L) ? q.k : 0, -inf diag.
// grid (W, B, 2): z selects 32 h-rows; 4 waves x 8 rows each.
// ---------------------------------------------------------------------------
__global__ __launch_bounds__(256) void energyH_kernel(
    const float* __restrict__ qt, const float* __restrict__ kt,
    float* __restrict__ eH, const int* __restrict__ len_p)
{
  const int tid = threadIdx.x;
  const int w = blockIdx.x, b = blockIdx.y, zz = blockIdx.z;
  int L = *len_p; L = L < 0 ? 0 : (L > 64 ? 64 : L);
  __shared__ float Qs[32][68];
  __shared__ float Ks[64][68];
  {
    const int c = tid & 63, grp = tid >> 6;
    const float* qb = qt + ((size_t)b * PP + w) * CQ + c;
    const float* kb = kt + ((size_t)b * PP + w) * CQ + c;
    #pragma unroll
    for (int r = 0; r < 8; ++r) {
      int hl = grp*8 + r;
      Qs[hl][c] = qb[(size_t)(zz*32 + hl) * WW * CQ];
    }
    #pragma unroll
    for (int r = 0; r < 16; ++r) {
      int hk = grp*16 + r;
      Ks[hk][c] = kb[(size_t)hk * WW * CQ];
    }
  }
  __syncthreads();
  const int g  = tid & 63;
  const int wg = tid >> 6;
  float kreg[64];
  #pragma unroll
  for (int c = 0; c < 64; ++c) kreg[c] = (c < L) ? Ks[g][c] : 0.0f;
  const bool gok = (g < L);
  float* ab = eH + (((size_t)b * HH) * WW + w) * 64 + g;
  for (int r = 0; r < 8; ++r) {
    int hl = wg*8 + r;
    int h  = zz*32 + hl;
    float e = 0.0f;
    #pragma unroll
    for (int c4 = 0; c4 < 16; ++c4) {
      float4 q4 = *(const float4*)&Qs[hl][4*c4];
      e += q4.x*kreg[4*c4+0] + q4.y*kreg[4*c4+1]
         + q4.z*kreg[4*c4+2] + q4.w*kreg[4*c4+3];
    }
    e = (gok && h < L) ? e : 0.0f;
    if (g == h) e = -INFINITY;
    ab[(size_t)h * WW * 64] = e;
  }
}

// ---------------------------------------------------------------------------
// energyW + softmax over [eH | eW]; writes bf16 probs to attHb / attWb.
// grid (H, B, 2): z selects 32 w-rows; 4 waves x 8 rows each.
// ---------------------------------------------------------------------------
__global__ __launch_bounds__(256) void energyW_softmax_kernel(
    const float* __restrict__ qt, const float* __restrict__ kt,
    const float* __restrict__ eH,
    __bf16* __restrict__ attHb, __bf16* __restrict__ attWb,
    const int* __restrict__ len_p)
{
  const int tid = threadIdx.x;
  const int h = blockIdx.x, b = blockIdx.y, zz = blockIdx.z;
  int L = *len_p; L = L < 0 ? 0 : (L > 64 ? 64 : L);
  __shared__ float Qs[32][68];
  __shared__ float Ks[64][68];
  {
    const int c = tid & 63, grp = tid >> 6;
    const float* qb = qt + ((size_t)b * PP + (size_t)h * WW) * CQ + c;
    const float* kb = kt + ((size_t)b * PP + (size_t)h * WW) * CQ + c;
    #pragma unroll
    for (int r = 0; r < 8; ++r) {
      int wl = grp*8 + r;
      Qs[wl][c] = qb[(size_t)(zz*32 + wl) * CQ];
    }
    #pragma unroll
    for (int r = 0; r < 16; ++r) {
      int wk = grp*16 + r;
      Ks[wk][c] = kb[(size_t)wk * CQ];
    }
  }
  __syncthreads();
  const int g  = tid & 63;
  const int wg = tid >> 6;
  float kreg[64];
  #pragma unroll
  for (int c = 0; c < 64; ++c) kreg[c] = (c < L) ? Ks[g][c] : 0.0f;
  const bool gok = (g < L);
  const float* ehb = eH + (((size_t)b * HH + h) * WW) * 64 + g;
  __bf16* ahb = attHb + (((size_t)b * HH + h) * WW) * 64 + g;
  __bf16* awb = attWb + (((size_t)b * HH + h) * WW) * 64 + g;
  for (int r = 0; r < 8; ++r) {
    int wl = wg*8 + r;
    int w  = zz*32 + wl;
    float e = 0.0f;
    #pragma unroll
    for (int c4 = 0; c4 < 16; ++c4) {
      float4 q4 = *(const float4*)&Qs[wl][4*c4];
      e += q4.x*kreg[4*c4+0] + q4.y*kreg[4*c4+1]
         + q4.z*kreg[4*c4+2] + q4.w*kreg[4*c4+3];
    }
    e = (gok && w < L) ? e : 0.0f;
    float eh = ehb[(size_t)w * 64];
    float m = fmaxf(e, eh);
    #pragma unroll
    for (int d = 32; d > 0; d >>= 1) m = fmaxf(m, __shfl_xor(m, d, 64));
    float pe = __expf(e  - m);
    float ph = __expf(eh - m);
    float s = pe + ph;
    #pragma unroll
    for (int d = 32; d > 0; d >>= 1) s += __shfl_xor(s, d, 64);
    float inv = 1.0f / s;
    ahb[(size_t)w * 64] = (__bf16)(ph * inv);
    awb[(size_t)w * 64] = (__bf16)(pe * inv);
  }
}

// ---------------------------------------------------------------------------
// V staging into 16x16-subtiled LDS (64j x 64c tile) with j-permutation so
// ds_read_b64_tr_b16 (lane addr = subtile_base + 8*l) yields B-fragments:
//   s=j>>5, p=(j>>2)&1, t=((j&31)>>3)*4+(j&3), cb=c>>4
//   entry offset = ((s*2+p)*4 + cb)*256 + t*16 + (c&15)   [bf16 entries]
// ---------------------------------------------------------------------------
__device__ __forceinline__ int vsub64_off(int j, int c) {
  int s  = j >> 5;
  int p  = (j >> 2) & 1;
  int t  = ((j & 31) >> 3) * 4 + (j & 3);
  return ((s*2 + p)*4 + (c >> 4))*256 + t*16 + (c & 15);
}

// ---------------------------------------------------------------------------
// outH (MFMA): per (b,w,cq): oH[b,h,w, cq*64+c'] = sum_j attH[h,j]*v[j*64+w,c]
// grid (W, 8, B), block 256 (4 waves; wave wv owns h rows wv*16..+15).
// ---------------------------------------------------------------------------
__global__ __launch_bounds__(256) void outH_mfma_kernel(
    const __bf16* __restrict__ attHb, const __bf16* __restrict__ vt,
    __bf16* __restrict__ oH)
{
  const int tid = threadIdx.x;
  const int w = blockIdx.x, cq = blockIdx.y, b = blockIdx.z;
  const int l = tid & 63, wv = tid >> 6;
  const int lm = l & 15, lk = l >> 4;

  __shared__ __align__(16) __bf16 Bs[4096];

  #pragma unroll
  for (int i = 0; i < 2; ++i) {
    int j  = i*32 + (tid >> 3);
    int c0 = (tid & 7) * 8;
    bf16x8 v8 = *(const bf16x8*)(vt + ((size_t)b*PP + (size_t)j*WW + w)*CH + cq*64 + c0);
    *(bf16x8*)&Bs[vsub64_off(j, c0)] = v8;
  }

  const int hrow = wv*16 + lm;
  const __bf16* ab = attHb + (((size_t)b*HH + hrow)*WW + w)*64;
  bf16x8 af[2];
  af[0] = *(const bf16x8*)(ab + lk*8);
  af[1] = *(const bf16x8*)(ab + 32 + lk*8);
  __syncthreads();

  const unsigned bs_base = lds_off(&Bs[0]);
  f32x4 acc[4];
  #pragma unroll
  for (int f = 0; f < 4; ++f) acc[f] = (f32x4){0.f,0.f,0.f,0.f};
  #pragma unroll
  for (int s = 0; s < 2; ++s) {
    bf16x8 bfr[4];
    #pragma unroll
    for (int f = 0; f < 4; ++f) {
      unsigned base = bs_base + (unsigned)((((s*2)*4 + f)*512)) + (unsigned)(l*8);
      bf16x4 t0 = ds_tr16(base);
      bf16x4 t1 = ds_tr16(base + 2048);   // p=1 block
      bfr[f] = __builtin_shufflevector(t0, t1, 0,1,2,3,4,5,6,7);
    }
    asm volatile("s_waitcnt lgkmcnt(0)");
    __builtin_amdgcn_sched_barrier(0);
    #pragma unroll
    for (int f = 0; f < 4; ++f)
      acc[f] = __builtin_amdgcn_mfma_f32_16x16x32_bf16(af[s], bfr[f], acc[f], 0,0,0);
  }
  __bf16* ob = oH + (((size_t)b * HH) * WW + w) * CH + cq*64;
  #pragma unroll
  for (int f = 0; f < 4; ++f) {
    #pragma unroll
    for (int r = 0; r < 4; ++r) {
      int h = wv*16 + lk*4 + r;
      ob[(size_t)h * WW * CH + f*16 + lm] = (__bf16)acc[f][r];
    }
  }
}

// ---------------------------------------------------------------------------
// outW (MFMA) + final: per (b,h,cq): out = gamma*(outW + oH) + x1
// grid (H, 8, B), block 256. oH + x1 prefetched into registers at start;
// LDS union: Bs (8KB) then Sc [64][69] f32 (17.7KB).
// ---------------------------------------------------------------------------
__global__ __launch_bounds__(256) void outW_final_kernel(
    const __bf16* __restrict__ attWb, const __bf16* __restrict__ vt,
    const __bf16* __restrict__ oH,
    const float* __restrict__ x1, const float* __restrict__ gamma_p,
    float* __restrict__ out)
{
  const int tid = threadIdx.x;
  const int h = blockIdx.x, cq = blockIdx.y, b = blockIdx.z;
  const int l = tid & 63, wv = tid >> 6;
  const int lm = l & 15, lk = l >> 4;
  const float gamma = *gamma_p;

  __shared__ __align__(16) char smem[64*69*4];   // 17664 B
  __bf16* Bs = (__bf16*)smem;                    // 4096 entries (8 KB)
  typedef float ScRow[69];
  ScRow* Sc = (ScRow*)smem;                      // [64][69] f32

  #pragma unroll
  for (int i = 0; i < 2; ++i) {
    int j  = i*32 + (tid >> 3);
    int c0 = (tid & 7) * 8;
    bf16x8 v8 = *(const bf16x8*)(vt + ((size_t)b*PP + (size_t)h*WW + j)*CH + cq*64 + c0);
    *(bf16x8*)&Bs[vsub64_off(j, c0)] = v8;
  }

  const int wrow = wv*16 + lm;
  const __bf16* ab = attWb + (((size_t)b*HH + h)*WW + wrow)*64;
  bf16x8 af[2];
  af[0] = *(const bf16x8*)(ab + lk*8);
  af[1] = *(const bf16x8*)(ab + 32 + lk*8);

  // final-pass layout prefetch (T14): lane -> (w = wl, c rows ci = cg*16+r2)
  const int wl = tid & 63, cg = tid >> 6;
  const __bf16* ohb = oH + ((((size_t)b*HH + h) * WW) + wl) * CH + cq*64 + cg*16;
  bf16x8 ohr[2];
  ohr[0] = *(const bf16x8*)(ohb);
  ohr[1] = *(const bf16x8*)(ohb + 8);
  float x1r[16];
  {
    const float* x1b = x1 + ((size_t)b*CH + cq*64 + cg*16)*PP + (size_t)h*WW + wl;
    #pragma unroll
    for (int r2 = 0; r2 < 16; ++r2)
      x1r[r2] = x1b[(size_t)r2 * PP];
  }
  __syncthreads();

  const unsigned bs_base = lds_off(&Bs[0]);
  f32x4 acc[4];
  #pragma unroll
  for (int f = 0; f < 4; ++f) acc[f] = (f32x4){0.f,0.f,0.f,0.f};
  #pragma unroll
  for (int s = 0; s < 2; ++s) {
    bf16x8 bfr[4];
    #pragma unroll
    for (int f = 0; f < 4; ++f) {
      unsigned base = bs_base + (unsigned)((((s*2)*4 + f)*512)) + (unsigned)(l*8);
      bf16x4 t0 = ds_tr16(base);
      bf16x4 t1 = ds_tr16(base + 2048);
      bfr[f] = __builtin_shufflevector(t0, t1, 0,1,2,3,4,5,6,7);
    }
    asm volatile("s_waitcnt lgkmcnt(0)");
    __builtin_amdgcn_sched_barrier(0);
    #pragma unroll
    for (int f = 0; f < 4; ++f)
      acc[f] = __builtin_amdgcn_mfma_f32_16x16x32_bf16(af[s], bfr[f], acc[f], 0,0,0);
  }

  __syncthreads();   // all tr16 reads of Bs done (Sc aliases Bs)
  #pragma unroll
  for (int f = 0; f < 4; ++f) {
    #pragma unroll
    for (int r = 0; r < 4; ++r)
      Sc[wv*16 + lk*4 + r][f*16 + lm] = acc[f][r];
  }
  __syncthreads();
  {
    float* obp = out + ((size_t)b*CH + cq*64 + cg*16)*PP + (size_t)h*WW + wl;
    #pragma unroll
    for (int r2 = 0; r2 < 16; ++r2) {
      float oh = (float)ohr[r2 >> 3][r2 & 7];
      obp[(size_t)r2 * PP] = gamma * (Sc[wl][cg*16 + r2] + oh) + x1r[r2];
    }
  }
}

// ---------------------------------------------------------------------------
extern "C" void kernel_launch(void* const* d_in, const int* in_sizes, int n_in,
                              void* d_out, int out_size, void* d_ws, size_t ws_size,
                              hipStream_t stream)
{
  const float* x1 = (const float*)d_in[0];
  const float* x2 = (const float*)d_in[1];
  const float* x3 = (const float*)d_in[2];
  const float* Wq = (const float*)d_in[3];
  const float* bq = (const float*)d_in[4];
  const float* Wk = (const float*)d_in[5];
  const float* bk = (const float*)d_in[6];
  const float* Wv = (const float*)d_in[7];
  const float* bv = (const float*)d_in[8];
  const float* gamma = (const float*)d_in[9];
  const int*   len   = (const int*)d_in[10];
  float* out = (float*)d_out;

  // workspace layout (96 MiB total):
  float*  q_t   = (float*)d_ws;                           // (B,P,64)   f32   8 MiB
  float*  k_t   = q_t + (size_t)BB * PP * CQ;             // (B,P,64)   f32   8 MiB
  float*  eH    = k_t + (size_t)BB * PP * CQ;             // (B,H,W,64) f32   8 MiB
  __bf16* attHb = (__bf16*)(eH + (size_t)BB * PP * 64);   // (B,H,W,64) bf16  4 MiB
  __bf16* attWb = attHb + (size_t)BB * PP * 64;           // (B,H,W,64) bf16  4 MiB
  __bf16* v_t   = attWb + (size_t)BB * PP * 64;           // (B,P,512)  bf16 32 MiB
  __bf16* oH    = v_t + (size_t)BB * PP * CH;             // (B,H,W,512)bf16 32 MiB

  dim3 blk(256);
  // all projections in ONE launch; hybrid swizzle: XCD-aligned per m-block
  // AND role-interleaved in launch order (see proj_all_kernel comment).
  proj_all_kernel<<<dim3(6 * BB * PP / 128), blk, 0, stream>>>(
      x3, Wv, bv, v_t,  x1, Wq, bq, q_t,  x2, Wk, bk, k_t);

  energyH_kernel<<<dim3(WW, BB, 2), blk, 0, stream>>>(q_t, k_t, eH, len);
  energyW_softmax_kernel<<<dim3(HH, BB, 2), blk, 0, stream>>>(q_t, k_t, eH, attHb, attWb, len);
  outH_mfma_kernel<<<dim3(WW, 8, BB), blk, 0, stream>>>(attHb, v_t, oH);
  outW_final_kernel<<<dim3(HH, 8, BB), blk, 0, stream>>>(attWb, v_t, oH, x1, gamma, out);
}